// Round 1
// baseline (481.268 us; speedup 1.0000x reference)
//
#include <hip/hip_runtime.h>
#include <math.h>

// SALAD head: x -> [f | s] GEMM, t GEMM, log-space Sinkhorn (5 iters, implicit
// dust row), p = exp(M+u+v), v_agg = 2*p@f - rowsum(p)*anchors, L2-normalize.
// Round 0: full fp32 (no MFMA) correctness baseline with structured kernels.

#define BATCH 32
#define NTOK  1025
#define DIM   768
#define KDIM  64
#define CDIM  128
#define TDIM  256
#define NM1   1024
#define ROWLEN 8448          // TDIM + KDIM*CDIM
#define NITER 5
#define INV_REG 10.0f        // 1/0.1
#define NSPLIT 16
#define LOG_A (-4.17438727f) // -log(65)
#define LOG_B (-6.93147181f) // -log(1024)

// ---------------- pack W = [Wf | Ws], bias = [bf | bs] ----------------
__global__ __launch_bounds__(256) void pack_w(
    const float* __restrict__ Wf, const float* __restrict__ Ws,
    const float* __restrict__ bf, const float* __restrict__ bs,
    float* __restrict__ W_all, float* __restrict__ bias_all)
{
    int idx = blockIdx.x * 256 + threadIdx.x;
    if (idx < DIM * 192) {
        int d = idx / 192;
        int c = idx - d * 192;
        W_all[idx] = (c < CDIM) ? Wf[d * CDIM + c] : Ws[d * KDIM + (c - CDIM)];
    }
    if (idx < 192) {
        bias_all[idx] = (idx < CDIM) ? bf[idx] : bs[idx - CDIM];
    }
}

// ---------------- fused f / s GEMM ----------------
// C(32768 x 192) = X(32768 x 768, strided batch rows) @ W_all(768 x 192)
// blockIdx.y 0,1 -> f output [b][n][c]; blockIdx.y 2 -> M[b][k][n] = (s+bs)*sharp/reg
// BM=128, BN=64, BK=16, 128 threads, 8x8 microtile.
// A staged in LDS (two-plane interleave so both float4 frag reads are
// contiguous across lanes); B streamed from global (L2-resident, 576 KB).
__global__ __launch_bounds__(128) void gemm_fs(
    const float* __restrict__ x, const float* __restrict__ W_all,
    const float* __restrict__ bias_all, const float* __restrict__ sharp_p,
    float* __restrict__ fmat, float* __restrict__ Mmat)
{
    __shared__ float As[16 * 136];   // [kk][plane0:64 | plane1:64 | pad 8]
    const int tid = threadIdx.x;
    const int tx = tid & 15;         // m-group: rows tx*8 .. tx*8+7
    const int ty = tid >> 4;         // c-group: cols ty*8 .. ty*8+7
    const int mBase = blockIdx.x * 128;
    const int cBase = blockIdx.y * 64;
    const int c0 = cBase + ty * 8;

    // staging: this thread stages row (mBase + tid), 16 k's per tile
    const int grow = mBase + tid;
    const float* xrow = x + ((size_t)(grow >> 10) * NTOK + 1 + (grow & 1023)) * DIM;
    const int sbase = ((tid >> 2) & 1) * 64 + (tid >> 3) * 4 + (tid & 3);

    float acc[8][8];
#pragma unroll
    for (int i = 0; i < 8; ++i)
#pragma unroll
        for (int j = 0; j < 8; ++j) acc[i][j] = 0.f;

    for (int k0 = 0; k0 < DIM; k0 += 16) {
        float4 g0 = *(const float4*)(xrow + k0 + 0);
        float4 g1 = *(const float4*)(xrow + k0 + 4);
        float4 g2 = *(const float4*)(xrow + k0 + 8);
        float4 g3 = *(const float4*)(xrow + k0 + 12);
        __syncthreads();
        As[ 0*136 + sbase] = g0.x; As[ 1*136 + sbase] = g0.y;
        As[ 2*136 + sbase] = g0.z; As[ 3*136 + sbase] = g0.w;
        As[ 4*136 + sbase] = g1.x; As[ 5*136 + sbase] = g1.y;
        As[ 6*136 + sbase] = g1.z; As[ 7*136 + sbase] = g1.w;
        As[ 8*136 + sbase] = g2.x; As[ 9*136 + sbase] = g2.y;
        As[10*136 + sbase] = g2.z; As[11*136 + sbase] = g2.w;
        As[12*136 + sbase] = g3.x; As[13*136 + sbase] = g3.y;
        As[14*136 + sbase] = g3.z; As[15*136 + sbase] = g3.w;
        __syncthreads();
#pragma unroll
        for (int kk = 0; kk < 16; ++kk) {
            float4 a0 = *(const float4*)&As[kk*136 + tx*4];
            float4 a1 = *(const float4*)&As[kk*136 + 64 + tx*4];
            const float* wr = W_all + (size_t)(k0 + kk) * 192 + c0;
            float4 b0 = *(const float4*)(wr);
            float4 b1 = *(const float4*)(wr + 4);
            float am[8] = {a0.x, a0.y, a0.z, a0.w, a1.x, a1.y, a1.z, a1.w};
            float bn[8] = {b0.x, b0.y, b0.z, b0.w, b1.x, b1.y, b1.z, b1.w};
#pragma unroll
            for (int i = 0; i < 8; ++i)
#pragma unroll
                for (int j = 0; j < 8; ++j)
                    acc[i][j] = fmaf(am[i], bn[j], acc[i][j]);
        }
    }

    float b8[8];
#pragma unroll
    for (int j = 0; j < 8; ++j) b8[j] = bias_all[c0 + j];

    if (blockIdx.y < 2) {
        // f output: [b*1024+n][c], c contiguous
#pragma unroll
        for (int i = 0; i < 8; ++i) {
            int m = mBase + tx * 8 + i;
            float4 w0 = make_float4(acc[i][0]+b8[0], acc[i][1]+b8[1],
                                    acc[i][2]+b8[2], acc[i][3]+b8[3]);
            float4 w1 = make_float4(acc[i][4]+b8[4], acc[i][5]+b8[5],
                                    acc[i][6]+b8[6], acc[i][7]+b8[7]);
            float* fp = fmat + (size_t)m * CDIM + c0;
            *(float4*)(fp)     = w0;
            *(float4*)(fp + 4) = w1;
        }
    } else {
        // M output: [b][k][n], n contiguous (transposed store)
        const float sc = sharp_p[0] * INV_REG;
        const int bb = mBase >> 10;
        const int nb = (mBase & 1023) + tx * 8;
#pragma unroll
        for (int j = 0; j < 8; ++j) {
            int k = c0 - 128 + j;
            float bj = b8[j];
            float4 w0 = make_float4((acc[0][j]+bj)*sc, (acc[1][j]+bj)*sc,
                                    (acc[2][j]+bj)*sc, (acc[3][j]+bj)*sc);
            float4 w1 = make_float4((acc[4][j]+bj)*sc, (acc[5][j]+bj)*sc,
                                    (acc[6][j]+bj)*sc, (acc[7][j]+bj)*sc);
            float* mp = Mmat + ((size_t)bb * KDIM + k) * NM1 + nb;
            *(float4*)(mp)     = w0;
            *(float4*)(mp + 4) = w1;
        }
    }
}

// ---------------- t = x[:,0,:] @ Wt + bt  (writes unnormalized into d_out) --
__global__ __launch_bounds__(256) void gemm_t(
    const float* __restrict__ x, const float* __restrict__ Wt,
    const float* __restrict__ bt, float* __restrict__ out)
{
    __shared__ float xr[DIM];
    const int b = blockIdx.x, c = threadIdx.x;
    const float* xp = x + (size_t)b * NTOK * DIM;
    for (int i = c; i < DIM; i += 256) xr[i] = xp[i];
    __syncthreads();
    float acc = bt[c];
#pragma unroll 8
    for (int d = 0; d < DIM; ++d) acc = fmaf(xr[d], Wt[(size_t)d * TDIM + c], acc);
    out[(size_t)b * ROWLEN + c] = acc;
}

// ---------------- Sinkhorn (log-domain, implicit dust row) ----------------
// one block per batch, 1024 threads (16 waves). u[65], v[1024] live in LDS.
__global__ __launch_bounds__(1024) void sinkhorn(
    const float* __restrict__ Mmat, const float* __restrict__ dust_p,
    float* __restrict__ u_out, float* __restrict__ v_out)
{
    __shared__ float us[65];
    __shared__ float vs[NM1];
    const int b = blockIdx.x, tid = threadIdx.x;
    const int wave = tid >> 6, lane = tid & 63;
    const float* Mb = Mmat + (size_t)b * KDIM * NM1;
    const float dustM = dust_p[0] * INV_REG;
    vs[tid] = 0.f;
    __syncthreads();

    for (int it = 0; it < NITER; ++it) {
        // u update: row-wise logsumexp over n (rows assigned to waves)
        for (int k = wave; k < 65; k += 16) {
            float mmax = -INFINITY, S = 0.f;
            const float* Mr = Mb + (size_t)(k < 64 ? k : 0) * NM1;
            for (int n = lane; n < NM1; n += 64) {
                float xv = (k < 64 ? Mr[n] : dustM) + vs[n];
                float nm = fmaxf(mmax, xv);
                S = S * __expf(mmax - nm) + __expf(xv - nm);
                mmax = nm;
            }
#pragma unroll
            for (int off = 32; off > 0; off >>= 1) {
                float m2 = __shfl_down(mmax, off);
                float S2 = __shfl_down(S, off);
                float nm = fmaxf(mmax, m2);
                S = S * __expf(mmax - nm) + S2 * __expf(m2 - nm);
                mmax = nm;
            }
            if (lane == 0) us[k] = LOG_A - (mmax + __logf(S));
        }
        __syncthreads();
        // v update: column-wise logsumexp over k (one column per thread)
        {
            float mmax = -INFINITY, S = 0.f;
            for (int k = 0; k < KDIM; ++k) {
                float xv = Mb[(size_t)k * NM1 + tid] + us[k];
                float nm = fmaxf(mmax, xv);
                S = S * __expf(mmax - nm) + __expf(xv - nm);
                mmax = nm;
            }
            {
                float xv = dustM + us[64];
                float nm = fmaxf(mmax, xv);
                S = S * __expf(mmax - nm) + __expf(xv - nm);
                mmax = nm;
            }
            vs[tid] = LOG_B - (mmax + __logf(S));
        }
        __syncthreads();
    }

    if (tid < 65) u_out[b * 65 + tid] = us[tid];
    v_out[(size_t)b * NM1 + tid] = vs[tid];
}

// ---------------- aggregation: partial v = p @ f over an n-slice ----------
// grid (BATCH, NSPLIT), 128 threads. Each block: 64 n of one batch.
// p computed once into LDS (coalesced M reads), then 8x8-microtile outer
// product from LDS; per-k rowsum partials computed by wave 0.
__global__ __launch_bounds__(128) void aggregate(
    const float* __restrict__ Mmat, const float* __restrict__ fmat,
    const float* __restrict__ u_in, const float* __restrict__ v_in,
    float* __restrict__ vpart, float* __restrict__ rspart)
{
    __shared__ float fs[32 * 128];   // f chunk [nn][c]
    __shared__ float ps[32 * 68];    // p chunk [nn][k], pad 68 (4-way on write)
    __shared__ float us[KDIM];
    __shared__ float vsh[64];
    const int b = blockIdx.x, ns = blockIdx.y;
    const int tid = threadIdx.x;
    const int tx = tid & 7;          // k-group: k = tx*8 .. +7
    const int ty = tid >> 3;         // c-group: c = ty*8 .. +7
    const int n0 = ns * 64;

    if (tid < 64) us[tid] = u_in[b * 65 + tid];
    else          vsh[tid - 64] = v_in[(size_t)b * NM1 + n0 + (tid - 64)];

    const float* Mb = Mmat + (size_t)b * KDIM * NM1;
    const float* fb = fmat + ((size_t)b * NM1 + n0) * CDIM;

    float acc[8][8];
#pragma unroll
    for (int i = 0; i < 8; ++i)
#pragma unroll
        for (int j = 0; j < 8; ++j) acc[i][j] = 0.f;
    float rsacc = 0.f;

    const int p_nn = tid & 31;
    const int p_kb = tid >> 5;       // 0..3

    for (int ch = 0; ch < 2; ++ch) {
        __syncthreads();
        // stage f chunk 32 x 128
        {
            const float* fsrc = fb + (size_t)(ch * 32) * CDIM;
#pragma unroll
            for (int q = 0; q < 8; ++q) {
                int idx = q * 128 + tid;
                int nn = idx >> 5, c4 = (idx & 31) * 4;
                *(float4*)&fs[nn * 128 + c4] = *(const float4*)(fsrc + (size_t)nn * CDIM + c4);
            }
        }
        // compute p chunk 32 n x 64 k
        {
            int nglob = n0 + ch * 32 + p_nn;
            float vv = vsh[ch * 32 + p_nn];
#pragma unroll
            for (int q = 0; q < 16; ++q) {
                int k = q * 4 + p_kb;
                ps[p_nn * 68 + k] = __expf(Mb[(size_t)k * NM1 + nglob] + us[k] + vv);
            }
        }
        __syncthreads();
        // rowsum partials (wave 0; k = tid)
        if (tid < 64) {
#pragma unroll
            for (int nn = 0; nn < 32; ++nn) rsacc += ps[nn * 68 + tid];
        }
        // outer product
#pragma unroll
        for (int nn = 0; nn < 32; ++nn) {
            float4 p0 = *(const float4*)&ps[nn * 68 + tx * 8];
            float4 p1 = *(const float4*)&ps[nn * 68 + tx * 8 + 4];
            float4 f0 = *(const float4*)&fs[nn * 128 + ty * 8];
            float4 f1 = *(const float4*)&fs[nn * 128 + ty * 8 + 4];
            float pv[8] = {p0.x, p0.y, p0.z, p0.w, p1.x, p1.y, p1.z, p1.w};
            float fv[8] = {f0.x, f0.y, f0.z, f0.w, f1.x, f1.y, f1.z, f1.w};
#pragma unroll
            for (int i = 0; i < 8; ++i)
#pragma unroll
                for (int j = 0; j < 8; ++j)
                    acc[i][j] = fmaf(pv[i], fv[j], acc[i][j]);
        }
    }

    float* vp = vpart + (size_t)(ns * BATCH + b) * (KDIM * CDIM);
#pragma unroll
    for (int i = 0; i < 8; ++i) {
        int k = tx * 8 + i;
        float4 w0 = make_float4(acc[i][0], acc[i][1], acc[i][2], acc[i][3]);
        float4 w1 = make_float4(acc[i][4], acc[i][5], acc[i][6], acc[i][7]);
        float* wp = vp + (size_t)k * CDIM + ty * 8;
        *(float4*)(wp)     = w0;
        *(float4*)(wp + 4) = w1;
    }
    if (tid < 64) rspart[(ns * BATCH + b) * KDIM + tid] = rsacc;
}

// ---------------- finalize: combine partials, anchors, L2-normalize -------
__global__ __launch_bounds__(256) void finalize(
    const float* __restrict__ vpart, const float* __restrict__ rspart,
    const float* __restrict__ anchors, float* __restrict__ out)
{
    __shared__ float rstot[KDIM];
    __shared__ float red[4];
    const int b = blockIdx.x, tid = threadIdx.x;
    const int lane = tid & 63, wave = tid >> 6;

    if (tid < KDIM) {
        float s = 0.f;
#pragma unroll
        for (int ns = 0; ns < NSPLIT; ++ns) s += rspart[(ns * BATCH + b) * KDIM + tid];
        rstot[tid] = s;
    }
    __syncthreads();

    float* orow = out + (size_t)b * ROWLEN;
    float tval = orow[tid];          // t part written by gemm_t
    float ss = tval * tval;
    float vals[32];
#pragma unroll
    for (int q = 0; q < 32; ++q) {
        int idx = q * 256 + tid;
        float s = 0.f;
#pragma unroll
        for (int ns = 0; ns < NSPLIT; ++ns)
            s += vpart[(size_t)(ns * BATCH + b) * (KDIM * CDIM) + idx];
        float val = 2.f * s - rstot[idx >> 7] * anchors[idx];
        vals[q] = val;
        ss += val * val;
    }
#pragma unroll
    for (int off = 32; off > 0; off >>= 1) ss += __shfl_down(ss, off);
    if (lane == 0) red[wave] = ss;
    __syncthreads();
    float tot = red[0] + red[1] + red[2] + red[3];
    float scale = 1.f / fmaxf(sqrtf(tot), 1e-12f);

    orow[tid] = tval * scale;
#pragma unroll
    for (int q = 0; q < 32; ++q)
        orow[TDIM + q * 256 + tid] = vals[q] * scale;
}

// ---------------- launcher ----------------
extern "C" void kernel_launch(void* const* d_in, const int* in_sizes, int n_in,
                              void* d_out, int out_size, void* d_ws, size_t ws_size,
                              hipStream_t stream)
{
    const float* x       = (const float*)d_in[0];
    const float* Wf      = (const float*)d_in[1];
    const float* bf      = (const float*)d_in[2];
    const float* Ws      = (const float*)d_in[3];
    const float* bs      = (const float*)d_in[4];
    const float* Wt      = (const float*)d_in[5];
    const float* bt      = (const float*)d_in[6];
    const float* anchors = (const float*)d_in[7];
    const float* dust    = (const float*)d_in[8];
    const float* sharp   = (const float*)d_in[9];
    float* out = (float*)d_out;

    float* ws       = (float*)d_ws;
    float* W_all    = ws;                                    // 147456
    float* bias_all = W_all + 147456;                        // 192
    float* Mmat     = bias_all + 192;                        // 32*64*1024   = 2097152
    float* fmat     = Mmat + (size_t)BATCH * KDIM * NM1;     // 32*1024*128  = 4194304
    float* u_buf    = fmat + (size_t)BATCH * NM1 * CDIM;     // 32*65        = 2080
    float* v_buf    = u_buf + BATCH * 65;                    // 32*1024      = 32768
    float* vpart    = v_buf + BATCH * NM1;                   // 16*32*8192   = 4194304
    float* rspart   = vpart + (size_t)NSPLIT * BATCH * KDIM * CDIM; // 16*32*64

    hipLaunchKernelGGL(pack_w, dim3(576), dim3(256), 0, stream,
                       Wf, Ws, bf, bs, W_all, bias_all);
    hipLaunchKernelGGL(gemm_fs, dim3(256, 3), dim3(128), 0, stream,
                       x, W_all, bias_all, sharp, fmat, Mmat);
    hipLaunchKernelGGL(gemm_t, dim3(BATCH), dim3(256), 0, stream,
                       x, Wt, bt, out);
    hipLaunchKernelGGL(sinkhorn, dim3(BATCH), dim3(1024), 0, stream,
                       Mmat, dust, u_buf, v_buf);
    hipLaunchKernelGGL(aggregate, dim3(BATCH, NSPLIT), dim3(128), 0, stream,
                       Mmat, fmat, u_buf, v_buf, vpart, rspart);
    hipLaunchKernelGGL(finalize, dim3(BATCH), dim3(256), 0, stream,
                       vpart, rspart, anchors, out);
}

// Round 2
// 410.264 us; speedup vs baseline: 1.1731x; 1.1731x over previous
//
#include <hip/hip_runtime.h>
#include <math.h>

// SALAD head. Round 2: f/s GEMM -> bf16 MFMA 16x16x32, LDS-free
// (A from HBM fp32 with in-register bf16 convert, B from L2 bf16 pre-pack).

#define BATCH 32
#define NTOK  1025
#define DIM   768
#define KDIM  64
#define CDIM  128
#define TDIM  256
#define NM1   1024
#define ROWLEN 8448          // TDIM + KDIM*CDIM
#define NITER 5
#define INV_REG 10.0f        // 1/0.1
#define NSPLIT 16
#define LOG_A (-4.17438727f) // -log(65)
#define LOG_B (-6.93147181f) // -log(1024)

typedef __attribute__((ext_vector_type(8))) short short8;
typedef __attribute__((ext_vector_type(4))) float floatx4;

__device__ __forceinline__ unsigned short bf16_rne(float f) {
    unsigned u = __builtin_bit_cast(unsigned, f);
    unsigned r = u + 0x7FFFu + ((u >> 16) & 1u);
    return (unsigned short)(r >> 16);
}

// ---------------- pack W -> bf16, transposed [n][k]; bias fp32 -------------
__global__ __launch_bounds__(256) void pack_w(
    const float* __restrict__ Wf, const float* __restrict__ Ws,
    const float* __restrict__ bf, const float* __restrict__ bs,
    short* __restrict__ Wt_bf, float* __restrict__ bias_all)
{
    int idx = blockIdx.x * 256 + threadIdx.x;   // n*DIM + k
    if (idx < 192 * DIM) {
        int n = idx / DIM, k = idx - n * DIM;
        float v = (n < CDIM) ? Wf[(size_t)k * CDIM + n] : Ws[(size_t)k * KDIM + (n - CDIM)];
        Wt_bf[idx] = (short)bf16_rne(v);
    }
    if (idx < 192) bias_all[idx] = (idx < CDIM) ? bf[idx] : bs[idx - CDIM];
}

// ---------------- fused f / s GEMM via MFMA ----------------
// C(32768 x 192) = X(32768 x 768) @ W(768 x 192), bf16 inputs / fp32 acc.
// Block: 256 thr = 4 waves; wave computes 16 rows x 192 cols = 12 frags.
// Grid: 512 blocks (BM=64). No LDS. A frags direct from x (fp32->bf16),
// B frags direct from L2-resident Wt_bf.
__global__ __launch_bounds__(256, 2) void gemm_fs(
    const float* __restrict__ x, const short* __restrict__ Wt_bf,
    const float* __restrict__ bias_all, const float* __restrict__ sharp_p,
    float* __restrict__ fmat, float* __restrict__ Mmat)
{
    const int tid  = threadIdx.x;
    const int wave = tid >> 6, lane = tid & 63;
    const int quad = lane >> 4, lrow = lane & 15;
    const int R = blockIdx.x * 64 + wave * 16;     // strip base row (global m)
    const int m = R + lrow;                        // this lane's A row
    const float* xrow = x + ((size_t)(m >> 10) * NTOK + 1 + (m & 1023)) * DIM + quad * 8;
    const short* wbase = Wt_bf + (size_t)lrow * DIM + quad * 8;

    floatx4 acc[12];
#pragma unroll
    for (int nf = 0; nf < 12; ++nf) acc[nf] = (floatx4){0.f, 0.f, 0.f, 0.f};

    // register pipeline: A fp32 triple-buffer (depth 3), B double-buffer
    float4 abuf[3][2];
    short8 bbuf[2][12];
#pragma unroll
    for (int p = 0; p < 3; ++p) {
        abuf[p][0] = *(const float4*)(xrow + p * 32);
        abuf[p][1] = *(const float4*)(xrow + p * 32 + 4);
    }
#pragma unroll
    for (int nf = 0; nf < 12; ++nf)
        bbuf[0][nf] = *(const short8*)(wbase + (size_t)nf * 16 * DIM);

#pragma unroll
    for (int kt = 0; kt < 24; ++kt) {
        const int ap = kt % 3, bp = kt & 1;
        // convert this step's A to bf16
        float4 a0 = abuf[ap][0], a1 = abuf[ap][1];
        short8 afrag;
        afrag[0] = (short)bf16_rne(a0.x); afrag[1] = (short)bf16_rne(a0.y);
        afrag[2] = (short)bf16_rne(a0.z); afrag[3] = (short)bf16_rne(a0.w);
        afrag[4] = (short)bf16_rne(a1.x); afrag[5] = (short)bf16_rne(a1.y);
        afrag[6] = (short)bf16_rne(a1.z); afrag[7] = (short)bf16_rne(a1.w);
        // prefetch B (kt+1) and A (kt+3)
        if (kt + 1 < 24) {
#pragma unroll
            for (int nf = 0; nf < 12; ++nf)
                bbuf[bp ^ 1][nf] = *(const short8*)(wbase + (size_t)nf * 16 * DIM + (kt + 1) * 32);
        }
        if (kt + 3 < 24) {
            abuf[ap][0] = *(const float4*)(xrow + (kt + 3) * 32);
            abuf[ap][1] = *(const float4*)(xrow + (kt + 3) * 32 + 4);
        }
        // 12 MFMAs
#pragma unroll
        for (int nf = 0; nf < 12; ++nf)
            acc[nf] = __builtin_amdgcn_mfma_f32_16x16x32_bf16(afrag, bbuf[bp][nf], acc[nf], 0, 0, 0);
    }

    // epilogue: C/D layout col = lane&15, row = quad*4 + reg
    const float sc = sharp_p[0] * INV_REG;
    const int bb = R >> 10;
    const int n0 = (R & 1023) + quad * 4;
#pragma unroll
    for (int nf = 0; nf < 12; ++nf) {
        const int c = nf * 16 + lrow;
        const float bias = bias_all[c];
        if (nf < 8) {
            float* fp = fmat + ((size_t)R + quad * 4) * CDIM + c;
#pragma unroll
            for (int j = 0; j < 4; ++j)
                fp[(size_t)j * CDIM] = acc[nf][j] + bias;
        } else {
            const int k = c - CDIM;
            float4 w = make_float4((acc[nf][0] + bias) * sc, (acc[nf][1] + bias) * sc,
                                   (acc[nf][2] + bias) * sc, (acc[nf][3] + bias) * sc);
            *(float4*)(Mmat + ((size_t)bb * KDIM + k) * NM1 + n0) = w;
        }
    }
}

// ---------------- t = x[:,0,:] @ Wt + bt  (writes unnormalized into d_out) --
__global__ __launch_bounds__(256) void gemm_t(
    const float* __restrict__ x, const float* __restrict__ Wt,
    const float* __restrict__ bt, float* __restrict__ out)
{
    __shared__ float xr[DIM];
    const int b = blockIdx.x, c = threadIdx.x;
    const float* xp = x + (size_t)b * NTOK * DIM;
    for (int i = c; i < DIM; i += 256) xr[i] = xp[i];
    __syncthreads();
    float acc = bt[c];
#pragma unroll 8
    for (int d = 0; d < DIM; ++d) acc = fmaf(xr[d], Wt[(size_t)d * TDIM + c], acc);
    out[(size_t)b * ROWLEN + c] = acc;
}

// ---------------- Sinkhorn (log-domain, implicit dust row) ----------------
__global__ __launch_bounds__(1024) void sinkhorn(
    const float* __restrict__ Mmat, const float* __restrict__ dust_p,
    float* __restrict__ u_out, float* __restrict__ v_out)
{
    __shared__ float us[65];
    __shared__ float vs[NM1];
    const int b = blockIdx.x, tid = threadIdx.x;
    const int wave = tid >> 6, lane = tid & 63;
    const float* Mb = Mmat + (size_t)b * KDIM * NM1;
    const float dustM = dust_p[0] * INV_REG;
    vs[tid] = 0.f;
    __syncthreads();

    for (int it = 0; it < NITER; ++it) {
        for (int k = wave; k < 65; k += 16) {
            float mmax = -INFINITY, S = 0.f;
            const float* Mr = Mb + (size_t)(k < 64 ? k : 0) * NM1;
            for (int n = lane; n < NM1; n += 64) {
                float xv = (k < 64 ? Mr[n] : dustM) + vs[n];
                float nm = fmaxf(mmax, xv);
                S = S * __expf(mmax - nm) + __expf(xv - nm);
                mmax = nm;
            }
#pragma unroll
            for (int off = 32; off > 0; off >>= 1) {
                float m2 = __shfl_down(mmax, off);
                float S2 = __shfl_down(S, off);
                float nm = fmaxf(mmax, m2);
                S = S * __expf(mmax - nm) + S2 * __expf(m2 - nm);
                mmax = nm;
            }
            if (lane == 0) us[k] = LOG_A - (mmax + __logf(S));
        }
        __syncthreads();
        {
            float mmax = -INFINITY, S = 0.f;
            for (int k = 0; k < KDIM; ++k) {
                float xv = Mb[(size_t)k * NM1 + tid] + us[k];
                float nm = fmaxf(mmax, xv);
                S = S * __expf(mmax - nm) + __expf(xv - nm);
                mmax = nm;
            }
            {
                float xv = dustM + us[64];
                float nm = fmaxf(mmax, xv);
                S = S * __expf(mmax - nm) + __expf(xv - nm);
                mmax = nm;
            }
            vs[tid] = LOG_B - (mmax + __logf(S));
        }
        __syncthreads();
    }

    if (tid < 65) u_out[b * 65 + tid] = us[tid];
    v_out[(size_t)b * NM1 + tid] = vs[tid];
}

// ---------------- aggregation: partial v = p @ f over an n-slice ----------
__global__ __launch_bounds__(128) void aggregate(
    const float* __restrict__ Mmat, const float* __restrict__ fmat,
    const float* __restrict__ u_in, const float* __restrict__ v_in,
    float* __restrict__ vpart, float* __restrict__ rspart)
{
    __shared__ float fs[32 * 128];
    __shared__ float ps[32 * 68];
    __shared__ float us[KDIM];
    __shared__ float vsh[64];
    const int b = blockIdx.x, ns = blockIdx.y;
    const int tid = threadIdx.x;
    const int tx = tid & 7;
    const int ty = tid >> 3;
    const int n0 = ns * 64;

    if (tid < 64) us[tid] = u_in[b * 65 + tid];
    else          vsh[tid - 64] = v_in[(size_t)b * NM1 + n0 + (tid - 64)];

    const float* Mb = Mmat + (size_t)b * KDIM * NM1;
    const float* fb = fmat + ((size_t)b * NM1 + n0) * CDIM;

    float acc[8][8];
#pragma unroll
    for (int i = 0; i < 8; ++i)
#pragma unroll
        for (int j = 0; j < 8; ++j) acc[i][j] = 0.f;
    float rsacc = 0.f;

    const int p_nn = tid & 31;
    const int p_kb = tid >> 5;

    for (int ch = 0; ch < 2; ++ch) {
        __syncthreads();
        {
            const float* fsrc = fb + (size_t)(ch * 32) * CDIM;
#pragma unroll
            for (int q = 0; q < 8; ++q) {
                int idx = q * 128 + tid;
                int nn = idx >> 5, c4 = (idx & 31) * 4;
                *(float4*)&fs[nn * 128 + c4] = *(const float4*)(fsrc + (size_t)nn * CDIM + c4);
            }
        }
        {
            int nglob = n0 + ch * 32 + p_nn;
            float vv = vsh[ch * 32 + p_nn];
#pragma unroll
            for (int q = 0; q < 16; ++q) {
                int k = q * 4 + p_kb;
                ps[p_nn * 68 + k] = __expf(Mb[(size_t)k * NM1 + nglob] + us[k] + vv);
            }
        }
        __syncthreads();
        if (tid < 64) {
#pragma unroll
            for (int nn = 0; nn < 32; ++nn) rsacc += ps[nn * 68 + tid];
        }
#pragma unroll
        for (int nn = 0; nn < 32; ++nn) {
            float4 p0 = *(const float4*)&ps[nn * 68 + tx * 8];
            float4 p1 = *(const float4*)&ps[nn * 68 + tx * 8 + 4];
            float4 f0 = *(const float4*)&fs[nn * 128 + ty * 8];
            float4 f1 = *(const float4*)&fs[nn * 128 + ty * 8 + 4];
            float pv[8] = {p0.x, p0.y, p0.z, p0.w, p1.x, p1.y, p1.z, p1.w};
            float fv[8] = {f0.x, f0.y, f0.z, f0.w, f1.x, f1.y, f1.z, f1.w};
#pragma unroll
            for (int i = 0; i < 8; ++i)
#pragma unroll
                for (int j = 0; j < 8; ++j)
                    acc[i][j] = fmaf(pv[i], fv[j], acc[i][j]);
        }
    }

    float* vp = vpart + (size_t)(ns * BATCH + b) * (KDIM * CDIM);
#pragma unroll
    for (int i = 0; i < 8; ++i) {
        int k = tx * 8 + i;
        float4 w0 = make_float4(acc[i][0], acc[i][1], acc[i][2], acc[i][3]);
        float4 w1 = make_float4(acc[i][4], acc[i][5], acc[i][6], acc[i][7]);
        float* wp = vp + (size_t)k * CDIM + ty * 8;
        *(float4*)(wp)     = w0;
        *(float4*)(wp + 4) = w1;
    }
    if (tid < 64) rspart[(ns * BATCH + b) * KDIM + tid] = rsacc;
}

// ---------------- finalize: combine partials, anchors, L2-normalize -------
__global__ __launch_bounds__(256) void finalize(
    const float* __restrict__ vpart, const float* __restrict__ rspart,
    const float* __restrict__ anchors, float* __restrict__ out)
{
    __shared__ float rstot[KDIM];
    __shared__ float red[4];
    const int b = blockIdx.x, tid = threadIdx.x;
    const int lane = tid & 63, wave = tid >> 6;

    if (tid < KDIM) {
        float s = 0.f;
#pragma unroll
        for (int ns = 0; ns < NSPLIT; ++ns) s += rspart[(ns * BATCH + b) * KDIM + tid];
        rstot[tid] = s;
    }
    __syncthreads();

    float* orow = out + (size_t)b * ROWLEN;
    float tval = orow[tid];
    float ss = tval * tval;
    float4 vals[8];
#pragma unroll
    for (int q = 0; q < 8; ++q) {
        int i4 = q * 256 + tid;            // float4 slot 0..2047
        float4 s = make_float4(0.f, 0.f, 0.f, 0.f);
#pragma unroll
        for (int ns = 0; ns < NSPLIT; ++ns) {
            const float4 v = *(const float4*)&vpart[(size_t)(ns * BATCH + b) * (KDIM * CDIM) + (size_t)i4 * 4];
            s.x += v.x; s.y += v.y; s.z += v.z; s.w += v.w;
        }
        float rs = rstot[i4 >> 5];
        const float4 an = *(const float4*)&anchors[(size_t)i4 * 4];
        float4 v;
        v.x = 2.f * s.x - rs * an.x;
        v.y = 2.f * s.y - rs * an.y;
        v.z = 2.f * s.z - rs * an.z;
        v.w = 2.f * s.w - rs * an.w;
        vals[q] = v;
        ss += v.x * v.x + v.y * v.y + v.z * v.z + v.w * v.w;
    }
#pragma unroll
    for (int off = 32; off > 0; off >>= 1) ss += __shfl_down(ss, off);
    if (lane == 0) red[wave] = ss;
    __syncthreads();
    float tot = red[0] + red[1] + red[2] + red[3];
    float scale = 1.f / fmaxf(sqrtf(tot), 1e-12f);

    orow[tid] = tval * scale;
#pragma unroll
    for (int q = 0; q < 8; ++q) {
        int i4 = q * 256 + tid;
        float4 v = vals[q];
        v.x *= scale; v.y *= scale; v.z *= scale; v.w *= scale;
        *(float4*)&orow[TDIM + (size_t)i4 * 4] = v;
    }
}

// ---------------- launcher ----------------
extern "C" void kernel_launch(void* const* d_in, const int* in_sizes, int n_in,
                              void* d_out, int out_size, void* d_ws, size_t ws_size,
                              hipStream_t stream)
{
    const float* x       = (const float*)d_in[0];
    const float* Wf      = (const float*)d_in[1];
    const float* bf      = (const float*)d_in[2];
    const float* Ws      = (const float*)d_in[3];
    const float* bs      = (const float*)d_in[4];
    const float* Wt      = (const float*)d_in[5];
    const float* bt      = (const float*)d_in[6];
    const float* anchors = (const float*)d_in[7];
    const float* dust    = (const float*)d_in[8];
    const float* sharp   = (const float*)d_in[9];
    float* out = (float*)d_out;

    char* base = (char*)d_ws;
    short* Wt_bf    = (short*)base;                          // 294912 B
    float* bias_all = (float*)(base + 294912);               // 192
    float* Mmat     = bias_all + 192;                        // 32*64*1024
    float* fmat     = Mmat + (size_t)BATCH * KDIM * NM1;     // 32*1024*128
    float* u_buf    = fmat + (size_t)BATCH * NM1 * CDIM;     // 32*65
    float* v_buf    = u_buf + BATCH * 65;                    // 32*1024
    float* vpart    = v_buf + BATCH * NM1;                   // 16*32*8192
    float* rspart   = vpart + (size_t)NSPLIT * BATCH * KDIM * CDIM; // 16*32*64

    hipLaunchKernelGGL(pack_w, dim3(576), dim3(256), 0, stream,
                       Wf, Ws, bf, bs, Wt_bf, bias_all);
    hipLaunchKernelGGL(gemm_fs, dim3(512), dim3(256), 0, stream,
                       x, Wt_bf, bias_all, sharp, fmat, Mmat);
    hipLaunchKernelGGL(gemm_t, dim3(BATCH), dim3(256), 0, stream,
                       x, Wt, bt, out);
    hipLaunchKernelGGL(sinkhorn, dim3(BATCH), dim3(1024), 0, stream,
                       Mmat, dust, u_buf, v_buf);
    hipLaunchKernelGGL(aggregate, dim3(BATCH, NSPLIT), dim3(128), 0, stream,
                       Mmat, fmat, u_buf, v_buf, vpart, rspart);
    hipLaunchKernelGGL(finalize, dim3(BATCH), dim3(256), 0, stream,
                       vpart, rspart, anchors, out);
}

// Round 3
// 300.745 us; speedup vs baseline: 1.6003x; 1.3642x over previous
//
#include <hip/hip_runtime.h>
#include <math.h>

// SALAD head. Round 3: gemm_fs -> m97-style LDS MFMA GEMM (frag-major packed
// B via global_load_lds, bf16 frag-major A in LDS); sinkhorn 4-way ILP
// logsumexp; gemm_t/finalize parallelized.

#define BATCH 32
#define NTOK  1025
#define DIM   768
#define KDIM  64
#define CDIM  128
#define TDIM  256
#define NM1   1024
#define ROWLEN 8448          // TDIM + KDIM*CDIM
#define NITER 5
#define INV_REG 10.0f        // 1/0.1
#define NSPLIT 16
#define LOG_A (-4.17438727f) // -log(65)
#define LOG_B (-6.93147181f) // -log(1024)

typedef __attribute__((ext_vector_type(8))) short short8;
typedef __attribute__((ext_vector_type(4))) float floatx4;

typedef __attribute__((address_space(3))) unsigned int lds_uint;
typedef const __attribute__((address_space(1))) unsigned int glb_uint;

__device__ __forceinline__ void gload_lds16(const void* g, void* l) {
    __builtin_amdgcn_global_load_lds((glb_uint*)g, (lds_uint*)l, 16, 0, 0);
}

__device__ __forceinline__ unsigned short bf16_rne(float f) {
    unsigned u = __builtin_bit_cast(unsigned, f);
    unsigned r = u + 0x7FFFu + ((u >> 16) & 1u);
    return (unsigned short)(r >> 16);
}

__device__ __forceinline__ short8 cvt8(float4 a, float4 b) {
    short8 r;
    r[0] = (short)bf16_rne(a.x); r[1] = (short)bf16_rne(a.y);
    r[2] = (short)bf16_rne(a.z); r[3] = (short)bf16_rne(a.w);
    r[4] = (short)bf16_rne(b.x); r[5] = (short)bf16_rne(b.y);
    r[6] = (short)bf16_rne(b.z); r[7] = (short)bf16_rne(b.w);
    return r;
}

// online logsumexp step / merge
__device__ __forceinline__ void lse_step(float& m, float& S, float x) {
    float nm = fmaxf(m, x);
    S = S * __expf(m - nm) + __expf(x - nm);
    m = nm;
}
__device__ __forceinline__ void lse_merge(float& m, float& S, float m2, float S2) {
    float nm = fmaxf(m, m2);
    S = S * __expf(m - nm) + S2 * __expf(m2 - nm);
    m = nm;
}

// ---------------- pack W into frag-major bf16 order ----------------
// element (g,nf,lane,j): W[col = nf*16 + (lane&15)][k = g*32 + (lane>>4)*8 + j]
// flat offset = ((g*12 + nf)*64 + lane)*8 + j.   g=0..23, nf=0..11.
__global__ __launch_bounds__(256) void pack_w(
    const float* __restrict__ Wf, const float* __restrict__ Ws,
    const float* __restrict__ bf, const float* __restrict__ bs,
    short* __restrict__ W_pack, float* __restrict__ bias_all)
{
    int idx = blockIdx.x * 256 + threadIdx.x;
    if (idx < 24 * 12 * 512) {
        int g    = idx / 6144;
        int rem  = idx - g * 6144;
        int nf   = rem >> 9;
        int rem2 = rem & 511;
        int lane = rem2 >> 3;
        int j    = rem2 & 7;
        int k = g * 32 + (lane >> 4) * 8 + j;
        int c = nf * 16 + (lane & 15);
        float v = (c < CDIM) ? Wf[(size_t)k * CDIM + c] : Ws[(size_t)k * KDIM + (c - CDIM)];
        W_pack[idx] = (short)bf16_rne(v);
    }
    if (idx < 192) bias_all[idx] = (idx < CDIM) ? bf[idx] : bs[idx - CDIM];
}

// ---------------- fused f / s GEMM via MFMA + LDS staging ----------------
// C(32768 x 192) = X @ W. 512 blocks x 256 thr (4 waves); wave = 16 rows x
// 192 cols (12 frags). Outer loop: 12 iters of BK=64. B chunk (24 KB) staged
// frag-major via global_load_lds; A chunk converted to bf16 frag-major in LDS.
__global__ __launch_bounds__(256, 2) void gemm_fs(
    const float* __restrict__ x, const short* __restrict__ W_pack,
    const float* __restrict__ bias_all, const float* __restrict__ sharp_p,
    float* __restrict__ fmat, float* __restrict__ Mmat)
{
    __shared__ __align__(16) short Bs[12288];  // 24 KB  [kk][nf][lane][8]
    __shared__ __align__(16) short As[4096];   //  8 KB  [wave][kk][lane][8]
    const int tid  = threadIdx.x;
    const int wave = tid >> 6, lane = tid & 63;
    const int quad = lane >> 4, lrow = lane & 15;
    const int R = blockIdx.x * 64 + wave * 16;

    // A staging: thread handles row (blockIdx.x*64 + tid>>2), 16 k's
    const int arow = blockIdx.x * 64 + (tid >> 2);
    const float* asrc = x + ((size_t)(arow >> 10) * NTOK + 1 + (arow & 1023)) * DIM + (tid & 3) * 16;
    const int r    = (tid >> 2) & 15;
    const int seg  = tid & 3;
    const int kk_w = seg >> 1;
    const int q0   = (seg & 1) * 2;
    short* adst0 = &As[(((tid >> 6) * 2 + kk_w) * 64 + q0 * 16 + r) * 8];
    short* adst1 = &As[(((tid >> 6) * 2 + kk_w) * 64 + (q0 + 1) * 16 + r) * 8];

    floatx4 acc[12];
#pragma unroll
    for (int nf = 0; nf < 12; ++nf) acc[nf] = (floatx4){0.f, 0.f, 0.f, 0.f};

    for (int ko = 0; ko < 12; ++ko) {
        __syncthreads();
        // stage B: 24 KB, contiguous, width-16 async
        const short* bsrc = W_pack + ko * 12288 + tid * 8;
#pragma unroll
        for (int i = 0; i < 6; ++i)
            gload_lds16(bsrc + i * 2048, &Bs[i * 2048 + tid * 8]);
        // stage A: 64 B fp32 -> 2 x b128 bf16 frag-major
        {
            const float* ap = asrc + ko * 64;
            float4 g0 = *(const float4*)(ap);
            float4 g1 = *(const float4*)(ap + 4);
            float4 g2 = *(const float4*)(ap + 8);
            float4 g3 = *(const float4*)(ap + 12);
            *(short8*)adst0 = cvt8(g0, g1);
            *(short8*)adst1 = cvt8(g2, g3);
        }
        __syncthreads();
#pragma unroll
        for (int kk = 0; kk < 2; ++kk) {
            short8 af = *(const short8*)&As[((wave * 2 + kk) * 64 + lane) * 8];
#pragma unroll
            for (int nf = 0; nf < 12; ++nf) {
                short8 bf8 = *(const short8*)&Bs[((kk * 12 + nf) * 64 + lane) * 8];
                acc[nf] = __builtin_amdgcn_mfma_f32_16x16x32_bf16(af, bf8, acc[nf], 0, 0, 0);
            }
        }
    }

    // epilogue: C/D layout col = lane&15, row = quad*4 + reg
    const float sc = sharp_p[0] * INV_REG;
    const int bb = R >> 10;
    const int n0 = (R & 1023) + quad * 4;
#pragma unroll
    for (int nf = 0; nf < 12; ++nf) {
        const int c = nf * 16 + lrow;
        const float bias = bias_all[c];
        if (nf < 8) {
            float* fp = fmat + ((size_t)R + quad * 4) * CDIM + c;
#pragma unroll
            for (int j = 0; j < 4; ++j)
                fp[(size_t)j * CDIM] = acc[nf][j] + bias;
        } else {
            const int k = c - CDIM;
            float4 w = make_float4((acc[nf][0] + bias) * sc, (acc[nf][1] + bias) * sc,
                                   (acc[nf][2] + bias) * sc, (acc[nf][3] + bias) * sc);
            *(float4*)(Mmat + ((size_t)bb * KDIM + k) * NM1 + n0) = w;
        }
    }
}

// ---------------- t partials: x[:,0,:] @ Wt split over 3 d-chunks ----------
__global__ __launch_bounds__(256) void gemm_t_split(
    const float* __restrict__ x, const float* __restrict__ Wt,
    float* __restrict__ tpart)
{
    __shared__ float xr[256];
    const int b = blockIdx.x, dy = blockIdx.y, c = threadIdx.x;
    xr[c] = x[(size_t)b * NTOK * DIM + (size_t)dy * 256 + c];
    __syncthreads();
    float acc = 0.f;
    const float* wp = Wt + (size_t)dy * 256 * TDIM + c;
#pragma unroll 8
    for (int d = 0; d < 256; ++d) acc = fmaf(xr[d], wp[(size_t)d * TDIM], acc);
    tpart[((size_t)dy * BATCH + b) * TDIM + c] = acc;
}

// ---------------- Sinkhorn (log-domain, implicit dust row, 4-way ILP) ------
__global__ __launch_bounds__(1024) void sinkhorn(
    const float* __restrict__ Mmat, const float* __restrict__ dust_p,
    float* __restrict__ u_out, float* __restrict__ v_out)
{
    __shared__ float us[65];
    __shared__ float vs[NM1];
    const int b = blockIdx.x, tid = threadIdx.x;
    const int wave = tid >> 6, lane = tid & 63;
    const float* Mb = Mmat + (size_t)b * KDIM * NM1;
    const float dustM = dust_p[0] * INV_REG;
    vs[tid] = 0.f;
    __syncthreads();

    for (int it = 0; it < NITER; ++it) {
        // u update: row-wise logsumexp over n; 4 independent chains
        for (int k = wave; k < 65; k += 16) {
            const bool dust = (k == 64);
            const float* Mr = Mb + (size_t)(dust ? 0 : k) * NM1;
            float mx[4] = {-INFINITY, -INFINITY, -INFINITY, -INFINITY};
            float ssum[4] = {0.f, 0.f, 0.f, 0.f};
#pragma unroll
            for (int i = 0; i < 16; ++i) {
                int n = lane + i * 64;
                float xv = (dust ? dustM : Mr[n]) + vs[n];
                lse_step(mx[i & 3], ssum[i & 3], xv);
            }
            lse_merge(mx[0], ssum[0], mx[1], ssum[1]);
            lse_merge(mx[2], ssum[2], mx[3], ssum[3]);
            lse_merge(mx[0], ssum[0], mx[2], ssum[2]);
            float mm = mx[0], S = ssum[0];
#pragma unroll
            for (int off = 32; off > 0; off >>= 1) {
                float m2 = __shfl_down(mm, off);
                float S2 = __shfl_down(S, off);
                lse_merge(mm, S, m2, S2);
            }
            if (lane == 0) us[k] = LOG_A - (mm + __logf(S));
        }
        __syncthreads();
        // v update: column-wise logsumexp over k; 4 independent chains
        {
            float mx[4] = {-INFINITY, -INFINITY, -INFINITY, -INFINITY};
            float ssum[4] = {0.f, 0.f, 0.f, 0.f};
#pragma unroll 4
            for (int q = 0; q < 16; ++q) {
                int k = q * 4;
                float x0 = Mb[(size_t)(k + 0) * NM1 + tid] + us[k + 0];
                float x1 = Mb[(size_t)(k + 1) * NM1 + tid] + us[k + 1];
                float x2 = Mb[(size_t)(k + 2) * NM1 + tid] + us[k + 2];
                float x3 = Mb[(size_t)(k + 3) * NM1 + tid] + us[k + 3];
                lse_step(mx[0], ssum[0], x0);
                lse_step(mx[1], ssum[1], x1);
                lse_step(mx[2], ssum[2], x2);
                lse_step(mx[3], ssum[3], x3);
            }
            lse_step(mx[0], ssum[0], dustM + us[64]);
            lse_merge(mx[0], ssum[0], mx[1], ssum[1]);
            lse_merge(mx[2], ssum[2], mx[3], ssum[3]);
            lse_merge(mx[0], ssum[0], mx[2], ssum[2]);
            vs[tid] = LOG_B - (mx[0] + __logf(ssum[0]));
        }
        __syncthreads();
    }

    if (tid < 65) u_out[b * 65 + tid] = us[tid];
    v_out[(size_t)b * NM1 + tid] = vs[tid];
}

// ---------------- aggregation: partial v = p @ f over an n-slice ----------
__global__ __launch_bounds__(128) void aggregate(
    const float* __restrict__ Mmat, const float* __restrict__ fmat,
    const float* __restrict__ u_in, const float* __restrict__ v_in,
    float* __restrict__ vpart, float* __restrict__ rspart)
{
    __shared__ float fs[32 * 128];
    __shared__ float ps[32 * 68];
    __shared__ float us[KDIM];
    __shared__ float vsh[64];
    const int b = blockIdx.x, ns = blockIdx.y;
    const int tid = threadIdx.x;
    const int tx = tid & 7;
    const int ty = tid >> 3;
    const int n0 = ns * 64;

    if (tid < 64) us[tid] = u_in[b * 65 + tid];
    else          vsh[tid - 64] = v_in[(size_t)b * NM1 + n0 + (tid - 64)];

    const float* Mb = Mmat + (size_t)b * KDIM * NM1;
    const float* fb = fmat + ((size_t)b * NM1 + n0) * CDIM;

    float acc[8][8];
#pragma unroll
    for (int i = 0; i < 8; ++i)
#pragma unroll
        for (int j = 0; j < 8; ++j) acc[i][j] = 0.f;
    float rsacc = 0.f;

    const int p_nn = tid & 31;
    const int p_kb = tid >> 5;

    for (int ch = 0; ch < 2; ++ch) {
        __syncthreads();
        {
            const float* fsrc = fb + (size_t)(ch * 32) * CDIM;
#pragma unroll
            for (int q = 0; q < 8; ++q) {
                int idx = q * 128 + tid;
                int nn = idx >> 5, c4 = (idx & 31) * 4;
                *(float4*)&fs[nn * 128 + c4] = *(const float4*)(fsrc + (size_t)nn * CDIM + c4);
            }
        }
        {
            int nglob = n0 + ch * 32 + p_nn;
            float vv = vsh[ch * 32 + p_nn];
#pragma unroll
            for (int q = 0; q < 16; ++q) {
                int k = q * 4 + p_kb;
                ps[p_nn * 68 + k] = __expf(Mb[(size_t)k * NM1 + nglob] + us[k] + vv);
            }
        }
        __syncthreads();
        if (tid < 64) {
#pragma unroll
            for (int nn = 0; nn < 32; ++nn) rsacc += ps[nn * 68 + tid];
        }
#pragma unroll
        for (int nn = 0; nn < 32; ++nn) {
            float4 p0 = *(const float4*)&ps[nn * 68 + tx * 8];
            float4 p1 = *(const float4*)&ps[nn * 68 + tx * 8 + 4];
            float4 f0 = *(const float4*)&fs[nn * 128 + ty * 8];
            float4 f1 = *(const float4*)&fs[nn * 128 + ty * 8 + 4];
            float pv[8] = {p0.x, p0.y, p0.z, p0.w, p1.x, p1.y, p1.z, p1.w};
            float fv[8] = {f0.x, f0.y, f0.z, f0.w, f1.x, f1.y, f1.z, f1.w};
#pragma unroll
            for (int i = 0; i < 8; ++i)
#pragma unroll
                for (int j = 0; j < 8; ++j)
                    acc[i][j] = fmaf(pv[i], fv[j], acc[i][j]);
        }
    }

    float* vp = vpart + (size_t)(ns * BATCH + b) * (KDIM * CDIM);
#pragma unroll
    for (int i = 0; i < 8; ++i) {
        int k = tx * 8 + i;
        float4 w0 = make_float4(acc[i][0], acc[i][1], acc[i][2], acc[i][3]);
        float4 w1 = make_float4(acc[i][4], acc[i][5], acc[i][6], acc[i][7]);
        float* wp = vp + (size_t)k * CDIM + ty * 8;
        *(float4*)(wp)     = w0;
        *(float4*)(wp + 4) = w1;
    }
    if (tid < 64) rspart[(ns * BATCH + b) * KDIM + tid] = rsacc;
}

// ---------------- reduce partials -> vagg + per-segment sumsq --------------
__global__ __launch_bounds__(256) void reduce_vagg(
    const float* __restrict__ vpart, const float* __restrict__ rspart,
    const float* __restrict__ anchors, float* __restrict__ vagg,
    float* __restrict__ sq)
{
    __shared__ float rst[8];
    __shared__ float red[4];
    const int b = blockIdx.x, segi = blockIdx.y, tid = threadIdx.x;
    const int lane = tid & 63, wave = tid >> 6;
    if (tid < 8) {
        float s = 0.f;
#pragma unroll
        for (int ns = 0; ns < NSPLIT; ++ns)
            s += rspart[(ns * BATCH + b) * KDIM + segi * 8 + tid];
        rst[tid] = s;
    }
    __syncthreads();
    const int i4 = segi * 256 + tid;          // float4 slot among 2048
    float4 s = make_float4(0.f, 0.f, 0.f, 0.f);
#pragma unroll
    for (int ns = 0; ns < NSPLIT; ++ns) {
        const float4 v = *(const float4*)&vpart[(size_t)(ns * BATCH + b) * (KDIM * CDIM) + (size_t)i4 * 4];
        s.x += v.x; s.y += v.y; s.z += v.z; s.w += v.w;
    }
    float rs = rst[tid >> 5];
    const float4 an = *(const float4*)&anchors[(size_t)i4 * 4];
    float4 v;
    v.x = 2.f * s.x - rs * an.x;
    v.y = 2.f * s.y - rs * an.y;
    v.z = 2.f * s.z - rs * an.z;
    v.w = 2.f * s.w - rs * an.w;
    *(float4*)&vagg[(size_t)b * (KDIM * CDIM) + (size_t)i4 * 4] = v;
    float ss = v.x * v.x + v.y * v.y + v.z * v.z + v.w * v.w;
#pragma unroll
    for (int off = 32; off > 0; off >>= 1) ss += __shfl_down(ss, off);
    if (lane == 0) red[wave] = ss;
    __syncthreads();
    if (tid == 0) sq[b * 8 + segi] = red[0] + red[1] + red[2] + red[3];
}

// ---------------- finalize: norm + scale everything ------------------------
__global__ __launch_bounds__(256) void finalize2(
    const float* __restrict__ tpart, const float* __restrict__ bt,
    const float* __restrict__ sq, const float* __restrict__ vagg,
    float* __restrict__ out)
{
    __shared__ float red[4];
    __shared__ float sc_sh;
    const int b = blockIdx.x, tid = threadIdx.x;
    const int lane = tid & 63, wave = tid >> 6;

    float t = bt[tid];
#pragma unroll
    for (int s = 0; s < 3; ++s) t += tpart[((size_t)s * BATCH + b) * TDIM + tid];
    float ss = t * t;
#pragma unroll
    for (int off = 32; off > 0; off >>= 1) ss += __shfl_down(ss, off);
    if (lane == 0) red[wave] = ss;
    __syncthreads();
    if (tid == 0) {
        float tot = red[0] + red[1] + red[2] + red[3];
#pragma unroll
        for (int i = 0; i < 8; ++i) tot += sq[b * 8 + i];
        sc_sh = 1.f / fmaxf(sqrtf(tot), 1e-12f);
    }
    __syncthreads();
    const float scale = sc_sh;
    float* orow = out + (size_t)b * ROWLEN;
    orow[tid] = t * scale;
    const float* va = vagg + (size_t)b * (KDIM * CDIM);
#pragma unroll
    for (int q = 0; q < 8; ++q) {
        int i4 = q * 256 + tid;
        float4 v = *(const float4*)&va[(size_t)i4 * 4];
        v.x *= scale; v.y *= scale; v.z *= scale; v.w *= scale;
        *(float4*)&orow[TDIM + (size_t)i4 * 4] = v;
    }
}

// ---------------- launcher ----------------
extern "C" void kernel_launch(void* const* d_in, const int* in_sizes, int n_in,
                              void* d_out, int out_size, void* d_ws, size_t ws_size,
                              hipStream_t stream)
{
    const float* x       = (const float*)d_in[0];
    const float* Wf      = (const float*)d_in[1];
    const float* bf      = (const float*)d_in[2];
    const float* Ws      = (const float*)d_in[3];
    const float* bs      = (const float*)d_in[4];
    const float* Wt      = (const float*)d_in[5];
    const float* bt      = (const float*)d_in[6];
    const float* anchors = (const float*)d_in[7];
    const float* dust    = (const float*)d_in[8];
    const float* sharp   = (const float*)d_in[9];
    float* out = (float*)d_out;

    char* base = (char*)d_ws;
    short* W_pack   = (short*)base;                          // 294912 B
    float* bias_all = (float*)(base + 294912);               // 192
    float* Mmat     = bias_all + 192;                        // 32*64*1024
    float* fmat     = Mmat + (size_t)BATCH * KDIM * NM1;     // 32*1024*128
    float* u_buf    = fmat + (size_t)BATCH * NM1 * CDIM;     // 32*65
    float* v_buf    = u_buf + BATCH * 65;                    // 32*1024
    float* vpart    = v_buf + BATCH * NM1;                   // 16*32*8192
    float* rspart   = vpart + (size_t)NSPLIT * BATCH * KDIM * CDIM; // 16*32*64
    float* tpart    = rspart + NSPLIT * BATCH * KDIM;        // 3*32*256
    float* sq       = tpart + 3 * BATCH * TDIM;              // 32*8
    float* vagg     = Mmat;  // alias: Mmat dead after aggregate

    hipLaunchKernelGGL(pack_w, dim3(576), dim3(256), 0, stream,
                       Wf, Ws, bf, bs, W_pack, bias_all);
    hipLaunchKernelGGL(gemm_fs, dim3(512), dim3(256), 0, stream,
                       x, W_pack, bias_all, sharp, fmat, Mmat);
    hipLaunchKernelGGL(gemm_t_split, dim3(BATCH, 3), dim3(256), 0, stream,
                       x, Wt, tpart);
    hipLaunchKernelGGL(sinkhorn, dim3(BATCH), dim3(1024), 0, stream,
                       Mmat, dust, u_buf, v_buf);
    hipLaunchKernelGGL(aggregate, dim3(BATCH, NSPLIT), dim3(128), 0, stream,
                       Mmat, fmat, u_buf, v_buf, vpart, rspart);
    hipLaunchKernelGGL(reduce_vagg, dim3(BATCH, 8), dim3(256), 0, stream,
                       vpart, rspart, anchors, vagg, sq);
    hipLaunchKernelGGL(finalize2, dim3(BATCH), dim3(256), 0, stream,
                       tpart, bt, sq, vagg, out);
}

// Round 4
// 257.947 us; speedup vs baseline: 1.8658x; 1.1659x over previous
//
#include <hip/hip_runtime.h>
#include <math.h>

// SALAD head. Round 4: sinkhorn -> 10 small full-GPU kernels (u/v ping-pong,
// two-pass LSE, one wave per row / one thread per column). Rest unchanged.

#define BATCH 32
#define NTOK  1025
#define DIM   768
#define KDIM  64
#define CDIM  128
#define TDIM  256
#define NM1   1024
#define ROWLEN 8448          // TDIM + KDIM*CDIM
#define NITER 5
#define INV_REG 10.0f        // 1/0.1
#define NSPLIT 16
#define LOG_A (-4.17438727f) // -log(65)
#define LOG_B (-6.93147181f) // -log(1024)

typedef __attribute__((ext_vector_type(8))) short short8;
typedef __attribute__((ext_vector_type(4))) float floatx4;

typedef __attribute__((address_space(3))) unsigned int lds_uint;
typedef const __attribute__((address_space(1))) unsigned int glb_uint;

__device__ __forceinline__ void gload_lds16(const void* g, void* l) {
    __builtin_amdgcn_global_load_lds((glb_uint*)g, (lds_uint*)l, 16, 0, 0);
}

__device__ __forceinline__ unsigned short bf16_rne(float f) {
    unsigned u = __builtin_bit_cast(unsigned, f);
    unsigned r = u + 0x7FFFu + ((u >> 16) & 1u);
    return (unsigned short)(r >> 16);
}

__device__ __forceinline__ short8 cvt8(float4 a, float4 b) {
    short8 r;
    r[0] = (short)bf16_rne(a.x); r[1] = (short)bf16_rne(a.y);
    r[2] = (short)bf16_rne(a.z); r[3] = (short)bf16_rne(a.w);
    r[4] = (short)bf16_rne(b.x); r[5] = (short)bf16_rne(b.y);
    r[6] = (short)bf16_rne(b.z); r[7] = (short)bf16_rne(b.w);
    return r;
}

// ---------------- pack W into frag-major bf16 order ----------------
__global__ __launch_bounds__(256) void pack_w(
    const float* __restrict__ Wf, const float* __restrict__ Ws,
    const float* __restrict__ bf, const float* __restrict__ bs,
    short* __restrict__ W_pack, float* __restrict__ bias_all)
{
    int idx = blockIdx.x * 256 + threadIdx.x;
    if (idx < 24 * 12 * 512) {
        int g    = idx / 6144;
        int rem  = idx - g * 6144;
        int nf   = rem >> 9;
        int rem2 = rem & 511;
        int lane = rem2 >> 3;
        int j    = rem2 & 7;
        int k = g * 32 + (lane >> 4) * 8 + j;
        int c = nf * 16 + (lane & 15);
        float v = (c < CDIM) ? Wf[(size_t)k * CDIM + c] : Ws[(size_t)k * KDIM + (c - CDIM)];
        W_pack[idx] = (short)bf16_rne(v);
    }
    if (idx < 192) bias_all[idx] = (idx < CDIM) ? bf[idx] : bs[idx - CDIM];
}

// ---------------- fused f / s GEMM via MFMA + LDS staging ----------------
__global__ __launch_bounds__(256, 2) void gemm_fs(
    const float* __restrict__ x, const short* __restrict__ W_pack,
    const float* __restrict__ bias_all, const float* __restrict__ sharp_p,
    float* __restrict__ fmat, float* __restrict__ Mmat)
{
    __shared__ __align__(16) short Bs[12288];  // 24 KB  [kk][nf][lane][8]
    __shared__ __align__(16) short As[4096];   //  8 KB  [wave][kk][lane][8]
    const int tid  = threadIdx.x;
    const int wave = tid >> 6, lane = tid & 63;
    const int quad = lane >> 4, lrow = lane & 15;
    const int R = blockIdx.x * 64 + wave * 16;

    const int arow = blockIdx.x * 64 + (tid >> 2);
    const float* asrc = x + ((size_t)(arow >> 10) * NTOK + 1 + (arow & 1023)) * DIM + (tid & 3) * 16;
    const int r    = (tid >> 2) & 15;
    const int seg  = tid & 3;
    const int kk_w = seg >> 1;
    const int q0   = (seg & 1) * 2;
    short* adst0 = &As[(((tid >> 6) * 2 + kk_w) * 64 + q0 * 16 + r) * 8];
    short* adst1 = &As[(((tid >> 6) * 2 + kk_w) * 64 + (q0 + 1) * 16 + r) * 8];

    floatx4 acc[12];
#pragma unroll
    for (int nf = 0; nf < 12; ++nf) acc[nf] = (floatx4){0.f, 0.f, 0.f, 0.f};

    for (int ko = 0; ko < 12; ++ko) {
        __syncthreads();
        const short* bsrc = W_pack + ko * 12288 + tid * 8;
#pragma unroll
        for (int i = 0; i < 6; ++i)
            gload_lds16(bsrc + i * 2048, &Bs[i * 2048 + tid * 8]);
        {
            const float* ap = asrc + ko * 64;
            float4 g0 = *(const float4*)(ap);
            float4 g1 = *(const float4*)(ap + 4);
            float4 g2 = *(const float4*)(ap + 8);
            float4 g3 = *(const float4*)(ap + 12);
            *(short8*)adst0 = cvt8(g0, g1);
            *(short8*)adst1 = cvt8(g2, g3);
        }
        __syncthreads();
#pragma unroll
        for (int kk = 0; kk < 2; ++kk) {
            short8 af = *(const short8*)&As[((wave * 2 + kk) * 64 + lane) * 8];
#pragma unroll
            for (int nf = 0; nf < 12; ++nf) {
                short8 bf8 = *(const short8*)&Bs[((kk * 12 + nf) * 64 + lane) * 8];
                acc[nf] = __builtin_amdgcn_mfma_f32_16x16x32_bf16(af, bf8, acc[nf], 0, 0, 0);
            }
        }
    }

    const float sc = sharp_p[0] * INV_REG;
    const int bb = R >> 10;
    const int n0 = (R & 1023) + quad * 4;
#pragma unroll
    for (int nf = 0; nf < 12; ++nf) {
        const int c = nf * 16 + lrow;
        const float bias = bias_all[c];
        if (nf < 8) {
            float* fp = fmat + ((size_t)R + quad * 4) * CDIM + c;
#pragma unroll
            for (int j = 0; j < 4; ++j)
                fp[(size_t)j * CDIM] = acc[nf][j] + bias;
        } else {
            const int k = c - CDIM;
            float4 w = make_float4((acc[nf][0] + bias) * sc, (acc[nf][1] + bias) * sc,
                                   (acc[nf][2] + bias) * sc, (acc[nf][3] + bias) * sc);
            *(float4*)(Mmat + ((size_t)bb * KDIM + k) * NM1 + n0) = w;
        }
    }
}

// ---------------- t partials: x[:,0,:] @ Wt split over 3 d-chunks ----------
__global__ __launch_bounds__(256) void gemm_t_split(
    const float* __restrict__ x, const float* __restrict__ Wt,
    float* __restrict__ tpart)
{
    __shared__ float xr[256];
    const int b = blockIdx.x, dy = blockIdx.y, c = threadIdx.x;
    xr[c] = x[(size_t)b * NTOK * DIM + (size_t)dy * 256 + c];
    __syncthreads();
    float acc = 0.f;
    const float* wp = Wt + (size_t)dy * 256 * TDIM + c;
#pragma unroll 8
    for (int d = 0; d < 256; ++d) acc = fmaf(xr[d], wp[(size_t)d * TDIM], acc);
    tpart[((size_t)dy * BATCH + b) * TDIM + c] = acc;
}

// ---------------- sinkhorn u-update: one wave per (b,k) row ----------------
// grid 520 x 256 (4 waves/block) = 2080 waves = 32 b x 65 k.
// u_k = LOG_A - LSE_n(M[k][n] + v[n]);   k==64 is the implicit dust row.
__global__ __launch_bounds__(256) void sink_u(
    const float* __restrict__ Mmat, const float* __restrict__ v_in,
    const float* __restrict__ dust_p, float* __restrict__ u_out)
{
    const int wv   = (blockIdx.x << 2) + (threadIdx.x >> 6);
    const int lane = threadIdx.x & 63;
    const int b = wv / 65, k = wv - b * 65;
    const float dustM = dust_p[0] * INV_REG;

    const float4* vp = (const float4*)(v_in + (size_t)b * NM1);
    float xs[16];
    if (k < 64) {
        const float4* Mp = (const float4*)(Mmat + ((size_t)b * KDIM + k) * NM1);
#pragma unroll
        for (int i = 0; i < 4; ++i) {
            float4 mv = Mp[i * 64 + lane];
            float4 vv = vp[i * 64 + lane];
            xs[i * 4 + 0] = mv.x + vv.x;
            xs[i * 4 + 1] = mv.y + vv.y;
            xs[i * 4 + 2] = mv.z + vv.z;
            xs[i * 4 + 3] = mv.w + vv.w;
        }
    } else {
#pragma unroll
        for (int i = 0; i < 4; ++i) {
            float4 vv = vp[i * 64 + lane];
            xs[i * 4 + 0] = dustM + vv.x;
            xs[i * 4 + 1] = dustM + vv.y;
            xs[i * 4 + 2] = dustM + vv.z;
            xs[i * 4 + 3] = dustM + vv.w;
        }
    }
    // pass 1: global max (tree + butterfly)
    float m = xs[0];
#pragma unroll
    for (int i = 1; i < 16; ++i) m = fmaxf(m, xs[i]);
#pragma unroll
    for (int off = 1; off < 64; off <<= 1) m = fmaxf(m, __shfl_xor(m, off));
    // pass 2: sum of exps
    float S = 0.f;
#pragma unroll
    for (int i = 0; i < 16; ++i) S += __expf(xs[i] - m);
#pragma unroll
    for (int off = 1; off < 64; off <<= 1) S += __shfl_xor(S, off);
    if (lane == 0) u_out[wv] = LOG_A - (m + __logf(S));
}

// ---------------- sinkhorn v-update: one thread per (b,n) column -----------
// grid (32, 4) x 256.  v_n = LOG_B - LSE_k(M[k][n] + u[k])  incl. dust row.
__global__ __launch_bounds__(256) void sink_v(
    const float* __restrict__ Mmat, const float* __restrict__ u_in,
    const float* __restrict__ dust_p, float* __restrict__ v_out)
{
    __shared__ float us[65];
    const int b = blockIdx.x, tid = threadIdx.x;
    const int n = blockIdx.y * 256 + tid;
    if (tid < 65) us[tid] = u_in[b * 65 + tid];
    __syncthreads();
    const float* Mb = Mmat + (size_t)b * KDIM * NM1 + n;
    float xs[64];
#pragma unroll
    for (int k = 0; k < 64; ++k) xs[k] = Mb[(size_t)k * NM1] + us[k];
    const float xd = dust_p[0] * INV_REG + us[64];
    float m = xd;
#pragma unroll
    for (int k = 0; k < 64; ++k) m = fmaxf(m, xs[k]);
    float S = __expf(xd - m);
#pragma unroll
    for (int k = 0; k < 64; ++k) S += __expf(xs[k] - m);
    v_out[(size_t)b * NM1 + n] = LOG_B - (m + __logf(S));
}

// ---------------- aggregation: partial v = p @ f over an n-slice ----------
__global__ __launch_bounds__(128) void aggregate(
    const float* __restrict__ Mmat, const float* __restrict__ fmat,
    const float* __restrict__ u_in, const float* __restrict__ v_in,
    float* __restrict__ vpart, float* __restrict__ rspart)
{
    __shared__ float fs[32 * 128];
    __shared__ float ps[32 * 68];
    __shared__ float us[KDIM];
    __shared__ float vsh[64];
    const int b = blockIdx.x, ns = blockIdx.y;
    const int tid = threadIdx.x;
    const int tx = tid & 7;
    const int ty = tid >> 3;
    const int n0 = ns * 64;

    if (tid < 64) us[tid] = u_in[b * 65 + tid];
    else          vsh[tid - 64] = v_in[(size_t)b * NM1 + n0 + (tid - 64)];

    const float* Mb = Mmat + (size_t)b * KDIM * NM1;
    const float* fb = fmat + ((size_t)b * NM1 + n0) * CDIM;

    float acc[8][8];
#pragma unroll
    for (int i = 0; i < 8; ++i)
#pragma unroll
        for (int j = 0; j < 8; ++j) acc[i][j] = 0.f;
    float rsacc = 0.f;

    const int p_nn = tid & 31;
    const int p_kb = tid >> 5;

    for (int ch = 0; ch < 2; ++ch) {
        __syncthreads();
        {
            const float* fsrc = fb + (size_t)(ch * 32) * CDIM;
#pragma unroll
            for (int q = 0; q < 8; ++q) {
                int idx = q * 128 + tid;
                int nn = idx >> 5, c4 = (idx & 31) * 4;
                *(float4*)&fs[nn * 128 + c4] = *(const float4*)(fsrc + (size_t)nn * CDIM + c4);
            }
        }
        {
            int nglob = n0 + ch * 32 + p_nn;
            float vv = vsh[ch * 32 + p_nn];
#pragma unroll
            for (int q = 0; q < 16; ++q) {
                int k = q * 4 + p_kb;
                ps[p_nn * 68 + k] = __expf(Mb[(size_t)k * NM1 + nglob] + us[k] + vv);
            }
        }
        __syncthreads();
        if (tid < 64) {
#pragma unroll
            for (int nn = 0; nn < 32; ++nn) rsacc += ps[nn * 68 + tid];
        }
#pragma unroll
        for (int nn = 0; nn < 32; ++nn) {
            float4 p0 = *(const float4*)&ps[nn * 68 + tx * 8];
            float4 p1 = *(const float4*)&ps[nn * 68 + tx * 8 + 4];
            float4 f0 = *(const float4*)&fs[nn * 128 + ty * 8];
            float4 f1 = *(const float4*)&fs[nn * 128 + ty * 8 + 4];
            float pv[8] = {p0.x, p0.y, p0.z, p0.w, p1.x, p1.y, p1.z, p1.w};
            float fv[8] = {f0.x, f0.y, f0.z, f0.w, f1.x, f1.y, f1.z, f1.w};
#pragma unroll
            for (int i = 0; i < 8; ++i)
#pragma unroll
                for (int j = 0; j < 8; ++j)
                    acc[i][j] = fmaf(pv[i], fv[j], acc[i][j]);
        }
    }

    float* vp = vpart + (size_t)(ns * BATCH + b) * (KDIM * CDIM);
#pragma unroll
    for (int i = 0; i < 8; ++i) {
        int k = tx * 8 + i;
        float4 w0 = make_float4(acc[i][0], acc[i][1], acc[i][2], acc[i][3]);
        float4 w1 = make_float4(acc[i][4], acc[i][5], acc[i][6], acc[i][7]);
        float* wp = vp + (size_t)k * CDIM + ty * 8;
        *(float4*)(wp)     = w0;
        *(float4*)(wp + 4) = w1;
    }
    if (tid < 64) rspart[(ns * BATCH + b) * KDIM + tid] = rsacc;
}

// ---------------- reduce partials -> vagg + per-segment sumsq --------------
__global__ __launch_bounds__(256) void reduce_vagg(
    const float* __restrict__ vpart, const float* __restrict__ rspart,
    const float* __restrict__ anchors, float* __restrict__ vagg,
    float* __restrict__ sq)
{
    __shared__ float rst[8];
    __shared__ float red[4];
    const int b = blockIdx.x, segi = blockIdx.y, tid = threadIdx.x;
    const int lane = tid & 63, wave = tid >> 6;
    if (tid < 8) {
        float s = 0.f;
#pragma unroll
        for (int ns = 0; ns < NSPLIT; ++ns)
            s += rspart[(ns * BATCH + b) * KDIM + segi * 8 + tid];
        rst[tid] = s;
    }
    __syncthreads();
    const int i4 = segi * 256 + tid;
    float4 s = make_float4(0.f, 0.f, 0.f, 0.f);
#pragma unroll
    for (int ns = 0; ns < NSPLIT; ++ns) {
        const float4 v = *(const float4*)&vpart[(size_t)(ns * BATCH + b) * (KDIM * CDIM) + (size_t)i4 * 4];
        s.x += v.x; s.y += v.y; s.z += v.z; s.w += v.w;
    }
    float rs = rst[tid >> 5];
    const float4 an = *(const float4*)&anchors[(size_t)i4 * 4];
    float4 v;
    v.x = 2.f * s.x - rs * an.x;
    v.y = 2.f * s.y - rs * an.y;
    v.z = 2.f * s.z - rs * an.z;
    v.w = 2.f * s.w - rs * an.w;
    *(float4*)&vagg[(size_t)b * (KDIM * CDIM) + (size_t)i4 * 4] = v;
    float ss = v.x * v.x + v.y * v.y + v.z * v.z + v.w * v.w;
#pragma unroll
    for (int off = 32; off > 0; off >>= 1) ss += __shfl_down(ss, off);
    if (lane == 0) red[wave] = ss;
    __syncthreads();
    if (tid == 0) sq[b * 8 + segi] = red[0] + red[1] + red[2] + red[3];
}

// ---------------- finalize: norm + scale everything ------------------------
__global__ __launch_bounds__(256) void finalize2(
    const float* __restrict__ tpart, const float* __restrict__ bt,
    const float* __restrict__ sq, const float* __restrict__ vagg,
    float* __restrict__ out)
{
    __shared__ float red[4];
    __shared__ float sc_sh;
    const int b = blockIdx.x, tid = threadIdx.x;
    const int lane = tid & 63, wave = tid >> 6;

    float t = bt[tid];
#pragma unroll
    for (int s = 0; s < 3; ++s) t += tpart[((size_t)s * BATCH + b) * TDIM + tid];
    float ss = t * t;
#pragma unroll
    for (int off = 32; off > 0; off >>= 1) ss += __shfl_down(ss, off);
    if (lane == 0) red[wave] = ss;
    __syncthreads();
    if (tid == 0) {
        float tot = red[0] + red[1] + red[2] + red[3];
#pragma unroll
        for (int i = 0; i < 8; ++i) tot += sq[b * 8 + i];
        sc_sh = 1.f / fmaxf(sqrtf(tot), 1e-12f);
    }
    __syncthreads();
    const float scale = sc_sh;
    float* orow = out + (size_t)b * ROWLEN;
    orow[tid] = t * scale;
    const float* va = vagg + (size_t)b * (KDIM * CDIM);
#pragma unroll
    for (int q = 0; q < 8; ++q) {
        int i4 = q * 256 + tid;
        float4 v = *(const float4*)&va[(size_t)i4 * 4];
        v.x *= scale; v.y *= scale; v.z *= scale; v.w *= scale;
        *(float4*)&orow[TDIM + (size_t)i4 * 4] = v;
    }
}

// ---------------- launcher ----------------
extern "C" void kernel_launch(void* const* d_in, const int* in_sizes, int n_in,
                              void* d_out, int out_size, void* d_ws, size_t ws_size,
                              hipStream_t stream)
{
    const float* x       = (const float*)d_in[0];
    const float* Wf      = (const float*)d_in[1];
    const float* bf      = (const float*)d_in[2];
    const float* Ws      = (const float*)d_in[3];
    const float* bs      = (const float*)d_in[4];
    const float* Wt      = (const float*)d_in[5];
    const float* bt      = (const float*)d_in[6];
    const float* anchors = (const float*)d_in[7];
    const float* dust    = (const float*)d_in[8];
    const float* sharp   = (const float*)d_in[9];
    float* out = (float*)d_out;

    char* base = (char*)d_ws;
    short* W_pack   = (short*)base;                          // 294912 B
    float* bias_all = (float*)(base + 294912);               // 192
    float* Mmat     = bias_all + 192;                        // 32*64*1024
    float* fmat     = Mmat + (size_t)BATCH * KDIM * NM1;     // 32*1024*128
    float* u_buf    = fmat + (size_t)BATCH * NM1 * CDIM;     // 32*65
    float* v_buf    = u_buf + BATCH * 65;                    // 32*1024
    float* vpart    = v_buf + BATCH * NM1;                   // 16*32*8192
    float* rspart   = vpart + (size_t)NSPLIT * BATCH * KDIM * CDIM; // 16*32*64
    float* tpart    = rspart + NSPLIT * BATCH * KDIM;        // 3*32*256
    float* sq       = tpart + 3 * BATCH * TDIM;              // 32*8
    float* vagg     = Mmat;  // alias: Mmat dead after aggregate

    hipLaunchKernelGGL(pack_w, dim3(576), dim3(256), 0, stream,
                       Wf, Ws, bf, bs, W_pack, bias_all);
    hipLaunchKernelGGL(gemm_fs, dim3(512), dim3(256), 0, stream,
                       x, W_pack, bias_all, sharp, fmat, Mmat);
    hipLaunchKernelGGL(gemm_t_split, dim3(BATCH, 3), dim3(256), 0, stream,
                       x, Wt, tpart);

    hipMemsetAsync(v_buf, 0, (size_t)BATCH * NM1 * sizeof(float), stream);
    for (int it = 0; it < NITER; ++it) {
        hipLaunchKernelGGL(sink_u, dim3(520), dim3(256), 0, stream,
                           Mmat, v_buf, dust, u_buf);
        hipLaunchKernelGGL(sink_v, dim3(BATCH, 4), dim3(256), 0, stream,
                           Mmat, u_buf, dust, v_buf);
    }

    hipLaunchKernelGGL(aggregate, dim3(BATCH, NSPLIT), dim3(128), 0, stream,
                       Mmat, fmat, u_buf, v_buf, vpart, rspart);
    hipLaunchKernelGGL(reduce_vagg, dim3(BATCH, 8), dim3(256), 0, stream,
                       vpart, rspart, anchors, vagg, sq);
    hipLaunchKernelGGL(finalize2, dim3(BATCH), dim3(256), 0, stream,
                       tpart, bt, sq, vagg, out);
}

// Round 5
// 248.081 us; speedup vs baseline: 1.9400x; 1.0398x over previous
//
#include <hip/hip_runtime.h>
#include <math.h>

// SALAD head. Round 5: aggregate 4x parallelism (NSPLIT=32, 256 thr),
// gemm_fs A-prefetch across the barrier pair, sink_v full-CU grid,
// sink_u<FIRST> replaces the v-memset.

#define BATCH 32
#define NTOK  1025
#define DIM   768
#define KDIM  64
#define CDIM  128
#define TDIM  256
#define NM1   1024
#define ROWLEN 8448          // TDIM + KDIM*CDIM
#define NITER 5
#define INV_REG 10.0f        // 1/0.1
#define NSPLIT 32
#define LOG_A (-4.17438727f) // -log(65)
#define LOG_B (-6.93147181f) // -log(1024)

typedef __attribute__((ext_vector_type(8))) short short8;
typedef __attribute__((ext_vector_type(4))) float floatx4;

typedef __attribute__((address_space(3))) unsigned int lds_uint;
typedef const __attribute__((address_space(1))) unsigned int glb_uint;

__device__ __forceinline__ void gload_lds16(const void* g, void* l) {
    __builtin_amdgcn_global_load_lds((glb_uint*)g, (lds_uint*)l, 16, 0, 0);
}

__device__ __forceinline__ unsigned short bf16_rne(float f) {
    unsigned u = __builtin_bit_cast(unsigned, f);
    unsigned r = u + 0x7FFFu + ((u >> 16) & 1u);
    return (unsigned short)(r >> 16);
}

__device__ __forceinline__ short8 cvt8(float4 a, float4 b) {
    short8 r;
    r[0] = (short)bf16_rne(a.x); r[1] = (short)bf16_rne(a.y);
    r[2] = (short)bf16_rne(a.z); r[3] = (short)bf16_rne(a.w);
    r[4] = (short)bf16_rne(b.x); r[5] = (short)bf16_rne(b.y);
    r[6] = (short)bf16_rne(b.z); r[7] = (short)bf16_rne(b.w);
    return r;
}

// ---------------- pack W into frag-major bf16 order ----------------
__global__ __launch_bounds__(256) void pack_w(
    const float* __restrict__ Wf, const float* __restrict__ Ws,
    const float* __restrict__ bf, const float* __restrict__ bs,
    short* __restrict__ W_pack, float* __restrict__ bias_all)
{
    int idx = blockIdx.x * 256 + threadIdx.x;
    if (idx < 24 * 12 * 512) {
        int g    = idx / 6144;
        int rem  = idx - g * 6144;
        int nf   = rem >> 9;
        int rem2 = rem & 511;
        int lane = rem2 >> 3;
        int j    = rem2 & 7;
        int k = g * 32 + (lane >> 4) * 8 + j;
        int c = nf * 16 + (lane & 15);
        float v = (c < CDIM) ? Wf[(size_t)k * CDIM + c] : Ws[(size_t)k * KDIM + (c - CDIM)];
        W_pack[idx] = (short)bf16_rne(v);
    }
    if (idx < 192) bias_all[idx] = (idx < CDIM) ? bf[idx] : bs[idx - CDIM];
}

// ---------------- fused f / s GEMM via MFMA + LDS staging ----------------
// A-loads for iteration ko+1 are issued before the second barrier of
// iteration ko, so their latency overlaps the MFMA phase.
__global__ __launch_bounds__(256, 2) void gemm_fs(
    const float* __restrict__ x, const short* __restrict__ W_pack,
    const float* __restrict__ bias_all, const float* __restrict__ sharp_p,
    float* __restrict__ fmat, float* __restrict__ Mmat)
{
    __shared__ __align__(16) short Bs[12288];  // 24 KB  [kk][nf][lane][8]
    __shared__ __align__(16) short As[4096];   //  8 KB  [wave][kk][lane][8]
    const int tid  = threadIdx.x;
    const int wave = tid >> 6, lane = tid & 63;
    const int quad = lane >> 4, lrow = lane & 15;
    const int R = blockIdx.x * 64 + wave * 16;

    const int arow = blockIdx.x * 64 + (tid >> 2);
    const float* asrc = x + ((size_t)(arow >> 10) * NTOK + 1 + (arow & 1023)) * DIM + (tid & 3) * 16;
    const int r    = (tid >> 2) & 15;
    const int seg  = tid & 3;
    const int kk_w = seg >> 1;
    const int q0   = (seg & 1) * 2;
    short* adst0 = &As[(((tid >> 6) * 2 + kk_w) * 64 + q0 * 16 + r) * 8];
    short* adst1 = &As[(((tid >> 6) * 2 + kk_w) * 64 + (q0 + 1) * 16 + r) * 8];

    floatx4 acc[12];
#pragma unroll
    for (int nf = 0; nf < 12; ++nf) acc[nf] = (floatx4){0.f, 0.f, 0.f, 0.f};

    // A prefetch for ko=0
    float4 g0 = *(const float4*)(asrc);
    float4 g1 = *(const float4*)(asrc + 4);
    float4 g2 = *(const float4*)(asrc + 8);
    float4 g3 = *(const float4*)(asrc + 12);

    for (int ko = 0; ko < 12; ++ko) {
        __syncthreads();
        // stage B: 24 KB, contiguous, width-16 async
        const short* bsrc = W_pack + ko * 12288 + tid * 8;
#pragma unroll
        for (int i = 0; i < 6; ++i)
            gload_lds16(bsrc + i * 2048, &Bs[i * 2048 + tid * 8]);
        // stage A (current regs), then prefetch next A
        *(short8*)adst0 = cvt8(g0, g1);
        *(short8*)adst1 = cvt8(g2, g3);
        if (ko < 11) {
            const float* ap = asrc + (ko + 1) * 64;
            g0 = *(const float4*)(ap);
            g1 = *(const float4*)(ap + 4);
            g2 = *(const float4*)(ap + 8);
            g3 = *(const float4*)(ap + 12);
        }
        __syncthreads();
#pragma unroll
        for (int kk = 0; kk < 2; ++kk) {
            short8 af = *(const short8*)&As[((wave * 2 + kk) * 64 + lane) * 8];
#pragma unroll
            for (int nf = 0; nf < 12; ++nf) {
                short8 bf8 = *(const short8*)&Bs[((kk * 12 + nf) * 64 + lane) * 8];
                acc[nf] = __builtin_amdgcn_mfma_f32_16x16x32_bf16(af, bf8, acc[nf], 0, 0, 0);
            }
        }
    }

    const float sc = sharp_p[0] * INV_REG;
    const int bb = R >> 10;
    const int n0 = (R & 1023) + quad * 4;
#pragma unroll
    for (int nf = 0; nf < 12; ++nf) {
        const int c = nf * 16 + lrow;
        const float bias = bias_all[c];
        if (nf < 8) {
            float* fp = fmat + ((size_t)R + quad * 4) * CDIM + c;
#pragma unroll
            for (int j = 0; j < 4; ++j)
                fp[(size_t)j * CDIM] = acc[nf][j] + bias;
        } else {
            const int k = c - CDIM;
            float4 w = make_float4((acc[nf][0] + bias) * sc, (acc[nf][1] + bias) * sc,
                                   (acc[nf][2] + bias) * sc, (acc[nf][3] + bias) * sc);
            *(float4*)(Mmat + ((size_t)bb * KDIM + k) * NM1 + n0) = w;
        }
    }
}

// ---------------- t partials: x[:,0,:] @ Wt split over 3 d-chunks ----------
__global__ __launch_bounds__(256) void gemm_t_split(
    const float* __restrict__ x, const float* __restrict__ Wt,
    float* __restrict__ tpart)
{
    __shared__ float xr[256];
    const int b = blockIdx.x, dy = blockIdx.y, c = threadIdx.x;
    xr[c] = x[(size_t)b * NTOK * DIM + (size_t)dy * 256 + c];
    __syncthreads();
    float acc = 0.f;
    const float* wp = Wt + (size_t)dy * 256 * TDIM + c;
#pragma unroll 8
    for (int d = 0; d < 256; ++d) acc = fmaf(xr[d], wp[(size_t)d * TDIM], acc);
    tpart[((size_t)dy * BATCH + b) * TDIM + c] = acc;
}

// ---------------- sinkhorn u-update: one wave per (b,k) row ----------------
// grid 520 x 256 (4 waves) = 2080 waves = 32 b x 65 k. FIRST: v == 0.
template<bool FIRST>
__global__ __launch_bounds__(256) void sink_u(
    const float* __restrict__ Mmat, const float* __restrict__ v_in,
    const float* __restrict__ dust_p, float* __restrict__ u_out)
{
    const int wv   = (blockIdx.x << 2) + (threadIdx.x >> 6);
    const int lane = threadIdx.x & 63;
    const int b = wv / 65, k = wv - b * 65;
    const float dustM = dust_p[0] * INV_REG;

    const float4* vp = (const float4*)(v_in + (size_t)b * NM1);
    float xs[16];
    if (k < 64) {
        const float4* Mp = (const float4*)(Mmat + ((size_t)b * KDIM + k) * NM1);
#pragma unroll
        for (int i = 0; i < 4; ++i) {
            float4 mv = Mp[i * 64 + lane];
            float4 vv = FIRST ? make_float4(0.f, 0.f, 0.f, 0.f) : vp[i * 64 + lane];
            xs[i * 4 + 0] = mv.x + vv.x;
            xs[i * 4 + 1] = mv.y + vv.y;
            xs[i * 4 + 2] = mv.z + vv.z;
            xs[i * 4 + 3] = mv.w + vv.w;
        }
    } else {
#pragma unroll
        for (int i = 0; i < 4; ++i) {
            float4 vv = FIRST ? make_float4(0.f, 0.f, 0.f, 0.f) : vp[i * 64 + lane];
            xs[i * 4 + 0] = dustM + vv.x;
            xs[i * 4 + 1] = dustM + vv.y;
            xs[i * 4 + 2] = dustM + vv.z;
            xs[i * 4 + 3] = dustM + vv.w;
        }
    }
    float m = xs[0];
#pragma unroll
    for (int i = 1; i < 16; ++i) m = fmaxf(m, xs[i]);
#pragma unroll
    for (int off = 1; off < 64; off <<= 1) m = fmaxf(m, __shfl_xor(m, off));
    float S = 0.f;
#pragma unroll
    for (int i = 0; i < 16; ++i) S += __expf(xs[i] - m);
#pragma unroll
    for (int off = 1; off < 64; off <<= 1) S += __shfl_xor(S, off);
    if (lane == 0) u_out[wv] = LOG_A - (m + __logf(S));
}

// ---------------- sinkhorn v-update: one thread per (b,n) column -----------
// grid (32, 8) x 128 = 256 blocks (full CU coverage).
__global__ __launch_bounds__(128) void sink_v(
    const float* __restrict__ Mmat, const float* __restrict__ u_in,
    const float* __restrict__ dust_p, float* __restrict__ v_out)
{
    __shared__ float us[65];
    const int b = blockIdx.x, tid = threadIdx.x;
    const int n = blockIdx.y * 128 + tid;
    if (tid < 65) us[tid] = u_in[b * 65 + tid];
    __syncthreads();
    const float* Mb = Mmat + (size_t)b * KDIM * NM1 + n;
    float xs[64];
#pragma unroll
    for (int k = 0; k < 64; ++k) xs[k] = Mb[(size_t)k * NM1] + us[k];
    const float xd = dust_p[0] * INV_REG + us[64];
    float m = xd;
#pragma unroll
    for (int k = 0; k < 64; ++k) m = fmaxf(m, xs[k]);
    float S = __expf(xd - m);
#pragma unroll
    for (int k = 0; k < 64; ++k) S += __expf(xs[k] - m);
    v_out[(size_t)b * NM1 + n] = LOG_B - (m + __logf(S));
}

// ---------------- aggregation: partial v = p @ f over a 32-n slice --------
// grid (BATCH, NSPLIT=32) x 256 thr. Per thread: 8k x 4c accumulators.
__global__ __launch_bounds__(256) void aggregate(
    const float* __restrict__ Mmat, const float* __restrict__ fmat,
    const float* __restrict__ u_in, const float* __restrict__ v_in,
    float* __restrict__ vpart, float* __restrict__ rspart)
{
    __shared__ float fs[32 * 128];   // 16 KB  [nn][c]
    __shared__ float ps[32 * 68];    // 8.5 KB [nn][k] pad 68
    __shared__ float us[KDIM];
    __shared__ float vsh[32];
    const int b = blockIdx.x, ns = blockIdx.y;
    const int tid = threadIdx.x;
    const int tx = tid & 7;          // k-group: k = tx*8 .. +7
    const int ty = tid >> 3;         // c-group: c = ty*4 .. +3 (0..31)
    const int n0 = ns * 32;

    if (tid < 64) us[tid] = u_in[b * 65 + tid];
    else if (tid < 96) vsh[tid - 64] = v_in[(size_t)b * NM1 + n0 + (tid - 64)];
    __syncthreads();

    // stage f: 32 x 128 = 1024 float4 / 256 thr
    const float* fb = fmat + ((size_t)b * NM1 + n0) * CDIM;
#pragma unroll
    for (int q = 0; q < 4; ++q) {
        int idx = q * 256 + tid;
        int nn = idx >> 5, c4 = (idx & 31) * 4;
        *(float4*)&fs[nn * 128 + c4] = *(const float4*)(fb + (size_t)nn * CDIM + c4);
    }
    // compute p: 32 nn x 64 k / 256 thr = 8 each (coalesced M rows)
    {
        const int p_nn = tid & 31, p_kb = tid >> 5;   // p_kb 0..7
        const float* Mb = Mmat + (size_t)b * KDIM * NM1 + n0 + p_nn;
        const float vv = vsh[p_nn];
#pragma unroll
        for (int q = 0; q < 8; ++q) {
            int k = q * 8 + p_kb;
            ps[p_nn * 68 + k] = __expf(Mb[(size_t)k * NM1] + us[k] + vv);
        }
    }
    __syncthreads();

    float rsacc = 0.f;
    if (tid < 64) {
#pragma unroll
        for (int nn = 0; nn < 32; ++nn) rsacc += ps[nn * 68 + tid];
    }
    float acc[8][4];
#pragma unroll
    for (int i = 0; i < 8; ++i)
#pragma unroll
        for (int j = 0; j < 4; ++j) acc[i][j] = 0.f;
#pragma unroll
    for (int nn = 0; nn < 32; ++nn) {
        float4 p0 = *(const float4*)&ps[nn * 68 + tx * 8];
        float4 p1 = *(const float4*)&ps[nn * 68 + tx * 8 + 4];
        float4 f0 = *(const float4*)&fs[nn * 128 + ty * 4];
        float pv[8] = {p0.x, p0.y, p0.z, p0.w, p1.x, p1.y, p1.z, p1.w};
        float fv[4] = {f0.x, f0.y, f0.z, f0.w};
#pragma unroll
        for (int i = 0; i < 8; ++i)
#pragma unroll
            for (int j = 0; j < 4; ++j)
                acc[i][j] = fmaf(pv[i], fv[j], acc[i][j]);
    }

    float* vp = vpart + (size_t)(ns * BATCH + b) * (KDIM * CDIM);
#pragma unroll
    for (int i = 0; i < 8; ++i) {
        int k = tx * 8 + i;
        *(float4*)(vp + (size_t)k * CDIM + ty * 4) =
            make_float4(acc[i][0], acc[i][1], acc[i][2], acc[i][3]);
    }
    if (tid < 64) rspart[(ns * BATCH + b) * KDIM + tid] = rsacc;
}

// ---------------- reduce partials -> vagg + per-segment sumsq --------------
__global__ __launch_bounds__(256) void reduce_vagg(
    const float* __restrict__ vpart, const float* __restrict__ rspart,
    const float* __restrict__ anchors, float* __restrict__ vagg,
    float* __restrict__ sq)
{
    __shared__ float rst[8];
    __shared__ float red[4];
    const int b = blockIdx.x, segi = blockIdx.y, tid = threadIdx.x;
    const int lane = tid & 63, wave = tid >> 6;
    if (tid < 8) {
        float s = 0.f;
#pragma unroll
        for (int ns = 0; ns < NSPLIT; ++ns)
            s += rspart[(ns * BATCH + b) * KDIM + segi * 8 + tid];
        rst[tid] = s;
    }
    __syncthreads();
    const int i4 = segi * 256 + tid;
    float4 s = make_float4(0.f, 0.f, 0.f, 0.f);
#pragma unroll
    for (int ns = 0; ns < NSPLIT; ++ns) {
        const float4 v = *(const float4*)&vpart[(size_t)(ns * BATCH + b) * (KDIM * CDIM) + (size_t)i4 * 4];
        s.x += v.x; s.y += v.y; s.z += v.z; s.w += v.w;
    }
    float rs = rst[tid >> 5];
    const float4 an = *(const float4*)&anchors[(size_t)i4 * 4];
    float4 v;
    v.x = 2.f * s.x - rs * an.x;
    v.y = 2.f * s.y - rs * an.y;
    v.z = 2.f * s.z - rs * an.z;
    v.w = 2.f * s.w - rs * an.w;
    *(float4*)&vagg[(size_t)b * (KDIM * CDIM) + (size_t)i4 * 4] = v;
    float ss = v.x * v.x + v.y * v.y + v.z * v.z + v.w * v.w;
#pragma unroll
    for (int off = 32; off > 0; off >>= 1) ss += __shfl_down(ss, off);
    if (lane == 0) red[wave] = ss;
    __syncthreads();
    if (tid == 0) sq[b * 8 + segi] = red[0] + red[1] + red[2] + red[3];
}

// ---------------- finalize: norm + scale everything ------------------------
__global__ __launch_bounds__(256) void finalize2(
    const float* __restrict__ tpart, const float* __restrict__ bt,
    const float* __restrict__ sq, const float* __restrict__ vagg,
    float* __restrict__ out)
{
    __shared__ float red[4];
    __shared__ float sc_sh;
    const int b = blockIdx.x, tid = threadIdx.x;
    const int lane = tid & 63, wave = tid >> 6;

    float t = bt[tid];
#pragma unroll
    for (int s = 0; s < 3; ++s) t += tpart[((size_t)s * BATCH + b) * TDIM + tid];
    float ss = t * t;
#pragma unroll
    for (int off = 32; off > 0; off >>= 1) ss += __shfl_down(ss, off);
    if (lane == 0) red[wave] = ss;
    __syncthreads();
    if (tid == 0) {
        float tot = red[0] + red[1] + red[2] + red[3];
#pragma unroll
        for (int i = 0; i < 8; ++i) tot += sq[b * 8 + i];
        sc_sh = 1.f / fmaxf(sqrtf(tot), 1e-12f);
    }
    __syncthreads();
    const float scale = sc_sh;
    float* orow = out + (size_t)b * ROWLEN;
    orow[tid] = t * scale;
    const float* va = vagg + (size_t)b * (KDIM * CDIM);
#pragma unroll
    for (int q = 0; q < 8; ++q) {
        int i4 = q * 256 + tid;
        float4 v = *(const float4*)&va[(size_t)i4 * 4];
        v.x *= scale; v.y *= scale; v.z *= scale; v.w *= scale;
        *(float4*)&orow[TDIM + (size_t)i4 * 4] = v;
    }
}

// ---------------- launcher ----------------
extern "C" void kernel_launch(void* const* d_in, const int* in_sizes, int n_in,
                              void* d_out, int out_size, void* d_ws, size_t ws_size,
                              hipStream_t stream)
{
    const float* x       = (const float*)d_in[0];
    const float* Wf      = (const float*)d_in[1];
    const float* bf      = (const float*)d_in[2];
    const float* Ws      = (const float*)d_in[3];
    const float* bs      = (const float*)d_in[4];
    const float* Wt      = (const float*)d_in[5];
    const float* bt      = (const float*)d_in[6];
    const float* anchors = (const float*)d_in[7];
    const float* dust    = (const float*)d_in[8];
    const float* sharp   = (const float*)d_in[9];
    float* out = (float*)d_out;

    char* base = (char*)d_ws;
    short* W_pack   = (short*)base;                          // 294912 B
    float* bias_all = (float*)(base + 294912);               // 192
    float* Mmat     = bias_all + 192;                        // 32*64*1024
    float* fmat     = Mmat + (size_t)BATCH * KDIM * NM1;     // 32*1024*128
    float* u_buf    = fmat + (size_t)BATCH * NM1 * CDIM;     // 32*65
    float* v_buf    = u_buf + BATCH * 65;                    // 32*1024
    float* vpart    = v_buf + BATCH * NM1;                   // 32*32*8192
    float* rspart   = vpart + (size_t)NSPLIT * BATCH * KDIM * CDIM; // 32*32*64
    float* tpart    = rspart + NSPLIT * BATCH * KDIM;        // 3*32*256
    float* sq       = tpart + 3 * BATCH * TDIM;              // 32*8
    float* vagg     = Mmat;  // alias: Mmat dead after aggregate

    hipLaunchKernelGGL(pack_w, dim3(576), dim3(256), 0, stream,
                       Wf, Ws, bf, bs, W_pack, bias_all);
    hipLaunchKernelGGL(gemm_fs, dim3(512), dim3(256), 0, stream,
                       x, W_pack, bias_all, sharp, fmat, Mmat);
    hipLaunchKernelGGL(gemm_t_split, dim3(BATCH, 3), dim3(256), 0, stream,
                       x, Wt, tpart);

    hipLaunchKernelGGL(HIP_KERNEL_NAME(sink_u<true>), dim3(520), dim3(256), 0, stream,
                       Mmat, v_buf, dust, u_buf);
    hipLaunchKernelGGL(sink_v, dim3(BATCH, 8), dim3(128), 0, stream,
                       Mmat, u_buf, dust, v_buf);
    for (int it = 1; it < NITER; ++it) {
        hipLaunchKernelGGL(HIP_KERNEL_NAME(sink_u<false>), dim3(520), dim3(256), 0, stream,
                           Mmat, v_buf, dust, u_buf);
        hipLaunchKernelGGL(sink_v, dim3(BATCH, 8), dim3(128), 0, stream,
                           Mmat, u_buf, dust, v_buf);
    }

    hipLaunchKernelGGL(aggregate, dim3(BATCH, NSPLIT), dim3(256), 0, stream,
                       Mmat, fmat, u_buf, v_buf, vpart, rspart);
    hipLaunchKernelGGL(reduce_vagg, dim3(BATCH, 8), dim3(256), 0, stream,
                       vpart, rspart, anchors, vagg, sq);
    hipLaunchKernelGGL(finalize2, dim3(BATCH), dim3(256), 0, stream,
                       tpart, bt, sq, vagg, out);
}

// Round 6
// 242.164 us; speedup vs baseline: 1.9874x; 1.0244x over previous
//
#include <hip/hip_runtime.h>
#include <math.h>

// SALAD head. Round 6: MFMA aggregation (p in A-frag regs, f as bf16 f_T
// B-frags), fmat -> bf16 transposed, reduce+finalize fused, pack+gemm_t
// fused. 13 dispatches.

#define BATCH 32
#define NTOK  1025
#define DIM   768
#define KDIM  64
#define CDIM  128
#define TDIM  256
#define NM1   1024
#define ROWLEN 8448          // TDIM + KDIM*CDIM
#define NITER 5
#define INV_REG 10.0f        // 1/0.1
#define NS_AGG 8             // n-slices in aggregation (128 tokens each)
#define LOG_A (-4.17438727f) // -log(65)
#define LOG_B (-6.93147181f) // -log(1024)

typedef __attribute__((ext_vector_type(8))) short short8;
typedef __attribute__((ext_vector_type(4))) float floatx4;

typedef __attribute__((address_space(3))) unsigned int lds_uint;
typedef const __attribute__((address_space(1))) unsigned int glb_uint;

__device__ __forceinline__ void gload_lds16(const void* g, void* l) {
    __builtin_amdgcn_global_load_lds((glb_uint*)g, (lds_uint*)l, 16, 0, 0);
}

__device__ __forceinline__ unsigned short bf16_rne(float f) {
    unsigned u = __builtin_bit_cast(unsigned, f);
    unsigned r = u + 0x7FFFu + ((u >> 16) & 1u);
    return (unsigned short)(r >> 16);
}

__device__ __forceinline__ short8 cvt8(float4 a, float4 b) {
    short8 r;
    r[0] = (short)bf16_rne(a.x); r[1] = (short)bf16_rne(a.y);
    r[2] = (short)bf16_rne(a.z); r[3] = (short)bf16_rne(a.w);
    r[4] = (short)bf16_rne(b.x); r[5] = (short)bf16_rne(b.y);
    r[6] = (short)bf16_rne(b.z); r[7] = (short)bf16_rne(b.w);
    return r;
}

// ---------------- prep: pack W (blocks 0..575) + t-GEMM (blocks 576..671) --
__global__ __launch_bounds__(256) void prep(
    const float* __restrict__ Wf, const float* __restrict__ Ws,
    const float* __restrict__ bf, const float* __restrict__ bs,
    const float* __restrict__ x, const float* __restrict__ Wt,
    short* __restrict__ W_pack, float* __restrict__ bias_all,
    float* __restrict__ tpart)
{
    __shared__ float xr[256];
    const int blk = blockIdx.x, tid = threadIdx.x;
    if (blk < 576) {
        int idx = blk * 256 + tid;   // < 147456 exactly
        int g    = idx / 6144;
        int rem  = idx - g * 6144;
        int nf   = rem >> 9;
        int rem2 = rem & 511;
        int lane = rem2 >> 3;
        int j    = rem2 & 7;
        int k = g * 32 + (lane >> 4) * 8 + j;
        int c = nf * 16 + (lane & 15);
        float v = (c < CDIM) ? Wf[(size_t)k * CDIM + c] : Ws[(size_t)k * KDIM + (c - CDIM)];
        W_pack[idx] = (short)bf16_rne(v);
        if (idx < 192) bias_all[idx] = (idx < CDIM) ? bf[idx] : bs[idx - CDIM];
    } else {
        int i = blk - 576;           // 0..95
        int b = i / 3, dy = i - b * 3;
        xr[tid] = x[(size_t)b * NTOK * DIM + (size_t)dy * 256 + tid];
        __syncthreads();
        float acc = 0.f;
        const float* wp = Wt + (size_t)dy * 256 * TDIM + tid;
#pragma unroll 8
        for (int d = 0; d < 256; ++d) acc = fmaf(xr[d], wp[(size_t)d * TDIM], acc);
        tpart[((size_t)dy * BATCH + b) * TDIM + tid] = acc;
    }
}

// ---------------- fused f / s GEMM via MFMA + LDS staging ----------------
// f output now bf16 TRANSPOSED: f_T[b][c][n]  (B-frag friendly for aggregate)
__global__ __launch_bounds__(256, 2) void gemm_fs(
    const float* __restrict__ x, const short* __restrict__ W_pack,
    const float* __restrict__ bias_all, const float* __restrict__ sharp_p,
    unsigned short* __restrict__ fT, float* __restrict__ Mmat)
{
    __shared__ __align__(16) short Bs[12288];  // 24 KB  [kk][nf][lane][8]
    __shared__ __align__(16) short As[4096];   //  8 KB  [wave][kk][lane][8]
    const int tid  = threadIdx.x;
    const int wave = tid >> 6, lane = tid & 63;
    const int quad = lane >> 4, lrow = lane & 15;
    const int R = blockIdx.x * 64 + wave * 16;

    const int arow = blockIdx.x * 64 + (tid >> 2);
    const float* asrc = x + ((size_t)(arow >> 10) * NTOK + 1 + (arow & 1023)) * DIM + (tid & 3) * 16;
    const int r    = (tid >> 2) & 15;
    const int seg  = tid & 3;
    const int kk_w = seg >> 1;
    const int q0   = (seg & 1) * 2;
    short* adst0 = &As[(((tid >> 6) * 2 + kk_w) * 64 + q0 * 16 + r) * 8];
    short* adst1 = &As[(((tid >> 6) * 2 + kk_w) * 64 + (q0 + 1) * 16 + r) * 8];

    floatx4 acc[12];
#pragma unroll
    for (int nf = 0; nf < 12; ++nf) acc[nf] = (floatx4){0.f, 0.f, 0.f, 0.f};

    float4 g0 = *(const float4*)(asrc);
    float4 g1 = *(const float4*)(asrc + 4);
    float4 g2 = *(const float4*)(asrc + 8);
    float4 g3 = *(const float4*)(asrc + 12);

    for (int ko = 0; ko < 12; ++ko) {
        __syncthreads();
        const short* bsrc = W_pack + ko * 12288 + tid * 8;
#pragma unroll
        for (int i = 0; i < 6; ++i)
            gload_lds16(bsrc + i * 2048, &Bs[i * 2048 + tid * 8]);
        *(short8*)adst0 = cvt8(g0, g1);
        *(short8*)adst1 = cvt8(g2, g3);
        if (ko < 11) {
            const float* ap = asrc + (ko + 1) * 64;
            g0 = *(const float4*)(ap);
            g1 = *(const float4*)(ap + 4);
            g2 = *(const float4*)(ap + 8);
            g3 = *(const float4*)(ap + 12);
        }
        __syncthreads();
#pragma unroll
        for (int kk = 0; kk < 2; ++kk) {
            short8 af = *(const short8*)&As[((wave * 2 + kk) * 64 + lane) * 8];
#pragma unroll
            for (int nf = 0; nf < 12; ++nf) {
                short8 bf8 = *(const short8*)&Bs[((kk * 12 + nf) * 64 + lane) * 8];
                acc[nf] = __builtin_amdgcn_mfma_f32_16x16x32_bf16(af, bf8, acc[nf], 0, 0, 0);
            }
        }
    }

    const float sc = sharp_p[0] * INV_REG;
    const int bb = R >> 10;
    const int tok = (R & 1023) + quad * 4;
#pragma unroll
    for (int nf = 0; nf < 12; ++nf) {
        const int c = nf * 16 + lrow;
        const float bias = bias_all[c];
        if (nf < 8) {
            // f_T[b][c][tok..tok+3] as bf16, one 8B store
            ushort4 w;
            w.x = bf16_rne(acc[nf][0] + bias);
            w.y = bf16_rne(acc[nf][1] + bias);
            w.z = bf16_rne(acc[nf][2] + bias);
            w.w = bf16_rne(acc[nf][3] + bias);
            *(ushort4*)(fT + ((size_t)bb * CDIM + c) * NM1 + tok) = w;
        } else {
            const int k = c - CDIM;
            float4 w = make_float4((acc[nf][0] + bias) * sc, (acc[nf][1] + bias) * sc,
                                   (acc[nf][2] + bias) * sc, (acc[nf][3] + bias) * sc);
            *(float4*)(Mmat + ((size_t)bb * KDIM + k) * NM1 + tok) = w;
        }
    }
}

// ---------------- sinkhorn u-update: one wave per (b,k) row ----------------
template<bool FIRST>
__global__ __launch_bounds__(256) void sink_u(
    const float* __restrict__ Mmat, const float* __restrict__ v_in,
    const float* __restrict__ dust_p, float* __restrict__ u_out)
{
    const int wv   = (blockIdx.x << 2) + (threadIdx.x >> 6);
    const int lane = threadIdx.x & 63;
    const int b = wv / 65, k = wv - b * 65;
    const float dustM = dust_p[0] * INV_REG;

    const float4* vp = (const float4*)(v_in + (size_t)b * NM1);
    float xs[16];
    if (k < 64) {
        const float4* Mp = (const float4*)(Mmat + ((size_t)b * KDIM + k) * NM1);
#pragma unroll
        for (int i = 0; i < 4; ++i) {
            float4 mv = Mp[i * 64 + lane];
            float4 vv = FIRST ? make_float4(0.f, 0.f, 0.f, 0.f) : vp[i * 64 + lane];
            xs[i * 4 + 0] = mv.x + vv.x;
            xs[i * 4 + 1] = mv.y + vv.y;
            xs[i * 4 + 2] = mv.z + vv.z;
            xs[i * 4 + 3] = mv.w + vv.w;
        }
    } else {
#pragma unroll
        for (int i = 0; i < 4; ++i) {
            float4 vv = FIRST ? make_float4(0.f, 0.f, 0.f, 0.f) : vp[i * 64 + lane];
            xs[i * 4 + 0] = dustM + vv.x;
            xs[i * 4 + 1] = dustM + vv.y;
            xs[i * 4 + 2] = dustM + vv.z;
            xs[i * 4 + 3] = dustM + vv.w;
        }
    }
    float m = xs[0];
#pragma unroll
    for (int i = 1; i < 16; ++i) m = fmaxf(m, xs[i]);
#pragma unroll
    for (int off = 1; off < 64; off <<= 1) m = fmaxf(m, __shfl_xor(m, off));
    float S = 0.f;
#pragma unroll
    for (int i = 0; i < 16; ++i) S += __expf(xs[i] - m);
#pragma unroll
    for (int off = 1; off < 64; off <<= 1) S += __shfl_xor(S, off);
    if (lane == 0) u_out[wv] = LOG_A - (m + __logf(S));
}

// ---------------- sinkhorn v-update: one thread per (b,n) column -----------
__global__ __launch_bounds__(128) void sink_v(
    const float* __restrict__ Mmat, const float* __restrict__ u_in,
    const float* __restrict__ dust_p, float* __restrict__ v_out)
{
    __shared__ float us[65];
    const int b = blockIdx.x, tid = threadIdx.x;
    const int n = blockIdx.y * 128 + tid;
    if (tid < 65) us[tid] = u_in[b * 65 + tid];
    __syncthreads();
    const float* Mb = Mmat + (size_t)b * KDIM * NM1 + n;
    float xs[64];
#pragma unroll
    for (int k = 0; k < 64; ++k) xs[k] = Mb[(size_t)k * NM1] + us[k];
    const float xd = dust_p[0] * INV_REG + us[64];
    float m = xd;
#pragma unroll
    for (int k = 0; k < 64; ++k) m = fmaxf(m, xs[k]);
    float S = __expf(xd - m);
#pragma unroll
    for (int k = 0; k < 64; ++k) S += __expf(xs[k] - m);
    v_out[(size_t)b * NM1 + n] = LOG_B - (m + __logf(S));
}

// ---------------- aggregation via MFMA: vpart[ns][b] = p_slice @ f_slice ---
// grid (BATCH, NS_AGG=8) x 256 thr (4 waves). Wave w: k-strip w*16..w*16+15,
// all 128 c. K-loop: 4 steps of 32 tokens. p computed in-register directly
// in A-frag layout (lane&15 = k-row, quad*8+j = token). f from bf16 f_T as
// B-frags. Rowsum in fp32 from unquantized p.
__global__ __launch_bounds__(256) void aggregate(
    const float* __restrict__ Mmat, const unsigned short* __restrict__ fT,
    const float* __restrict__ u_in, const float* __restrict__ v_in,
    float* __restrict__ vpart, float* __restrict__ rspart)
{
    __shared__ float us[KDIM];
    __shared__ float vsh[128];
    const int b = blockIdx.x, ns = blockIdx.y;
    const int tid = threadIdx.x;
    const int wave = tid >> 6, lane = tid & 63;
    const int quad = lane >> 4, lrow = lane & 15;

    if (tid < 64) us[tid] = u_in[b * 65 + tid];
    else if (tid < 192) vsh[tid - 64] = v_in[(size_t)b * NM1 + ns * 128 + (tid - 64)];
    __syncthreads();

    const int krow = wave * 16 + lrow;
    const float uk = us[krow];
    const float* Mrow = Mmat + ((size_t)b * KDIM + krow) * NM1 + ns * 128 + quad * 8;
    const unsigned short* fbase = fT + ((size_t)b * CDIM + lrow) * NM1 + ns * 128 + quad * 8;

    floatx4 acc[8];
#pragma unroll
    for (int nf = 0; nf < 8; ++nf) acc[nf] = (floatx4){0.f, 0.f, 0.f, 0.f};
    float rs = 0.f;

#pragma unroll
    for (int step = 0; step < 4; ++step) {
        const float* mp = Mrow + step * 32;
        float4 m0 = *(const float4*)(mp);
        float4 m1 = *(const float4*)(mp + 4);
        const int tb = step * 32 + quad * 8;
        float p[8];
        p[0] = __expf(m0.x + uk + vsh[tb + 0]);
        p[1] = __expf(m0.y + uk + vsh[tb + 1]);
        p[2] = __expf(m0.z + uk + vsh[tb + 2]);
        p[3] = __expf(m0.w + uk + vsh[tb + 3]);
        p[4] = __expf(m1.x + uk + vsh[tb + 4]);
        p[5] = __expf(m1.y + uk + vsh[tb + 5]);
        p[6] = __expf(m1.z + uk + vsh[tb + 6]);
        p[7] = __expf(m1.w + uk + vsh[tb + 7]);
        short8 afrag;
#pragma unroll
        for (int j = 0; j < 8; ++j) {
            rs += p[j];
            afrag[j] = (short)bf16_rne(p[j]);
        }
#pragma unroll
        for (int nf = 0; nf < 8; ++nf) {
            short8 bfrag = *(const short8*)(fbase + (size_t)nf * 16 * NM1 + step * 32);
            acc[nf] = __builtin_amdgcn_mfma_f32_16x16x32_bf16(afrag, bfrag, acc[nf], 0, 0, 0);
        }
    }

    // rowsum: combine the 4 quads holding the same k-row
    rs += __shfl_xor(rs, 16);
    rs += __shfl_xor(rs, 32);
    if (lane < 16) rspart[(ns * BATCH + b) * KDIM + krow] = rs;

    // C layout: col = lane&15, row = quad*4 + reg
    float* vp = vpart + (size_t)(ns * BATCH + b) * (KDIM * CDIM);
#pragma unroll
    for (int nf = 0; nf < 8; ++nf) {
        const int c = nf * 16 + lrow;
#pragma unroll
        for (int j = 0; j < 4; ++j)
            vp[(size_t)(wave * 16 + quad * 4 + j) * CDIM + c] = acc[nf][j];
    }
}

// ---------------- finalize: reduce partials, anchors, L2-normalize ---------
// grid BATCH x 1024 thr; thread owns 8 consecutive v_local floats.
__global__ __launch_bounds__(1024) void finalize_all(
    const float* __restrict__ vpart, const float* __restrict__ rspart,
    const float* __restrict__ anchors, const float* __restrict__ tpart,
    const float* __restrict__ bt, float* __restrict__ out)
{
    __shared__ float rstot[KDIM];
    __shared__ float red[16];
    __shared__ float sc_sh;
    const int b = blockIdx.x, tid = threadIdx.x;
    const int lane = tid & 63, wave = tid >> 6;

    if (tid < KDIM) {
        float s = 0.f;
#pragma unroll
        for (int ns = 0; ns < NS_AGG; ++ns)
            s += rspart[(ns * BATCH + b) * KDIM + tid];
        rstot[tid] = s;
    }
    __syncthreads();

    const size_t e0 = (size_t)tid * 8;
    float4 s0 = make_float4(0.f, 0.f, 0.f, 0.f);
    float4 s1 = make_float4(0.f, 0.f, 0.f, 0.f);
#pragma unroll
    for (int ns = 0; ns < NS_AGG; ++ns) {
        const float* vp = vpart + (size_t)(ns * BATCH + b) * (KDIM * CDIM) + e0;
        float4 a = *(const float4*)(vp);
        float4 c = *(const float4*)(vp + 4);
        s0.x += a.x; s0.y += a.y; s0.z += a.z; s0.w += a.w;
        s1.x += c.x; s1.y += c.y; s1.z += c.z; s1.w += c.w;
    }
    const float rsv = rstot[tid >> 4];
    float4 a0 = *(const float4*)(anchors + e0);
    float4 a1 = *(const float4*)(anchors + e0 + 4);
    float4 v0, v1;
    v0.x = 2.f * s0.x - rsv * a0.x;  v0.y = 2.f * s0.y - rsv * a0.y;
    v0.z = 2.f * s0.z - rsv * a0.z;  v0.w = 2.f * s0.w - rsv * a0.w;
    v1.x = 2.f * s1.x - rsv * a1.x;  v1.y = 2.f * s1.y - rsv * a1.y;
    v1.z = 2.f * s1.z - rsv * a1.z;  v1.w = 2.f * s1.w - rsv * a1.w;
    float ss = v0.x*v0.x + v0.y*v0.y + v0.z*v0.z + v0.w*v0.w
             + v1.x*v1.x + v1.y*v1.y + v1.z*v1.z + v1.w*v1.w;

    float t = 0.f;
    if (tid < TDIM) {
        t = bt[tid];
#pragma unroll
        for (int s = 0; s < 3; ++s) t += tpart[((size_t)s * BATCH + b) * TDIM + tid];
        ss += t * t;
    }

#pragma unroll
    for (int off = 32; off > 0; off >>= 1) ss += __shfl_down(ss, off);
    if (lane == 0) red[wave] = ss;
    __syncthreads();
    if (tid == 0) {
        float tot = 0.f;
#pragma unroll
        for (int i = 0; i < 16; ++i) tot += red[i];
        sc_sh = 1.f / fmaxf(sqrtf(tot), 1e-12f);
    }
    __syncthreads();
    const float scale = sc_sh;

    float* orow = out + (size_t)b * ROWLEN;
    if (tid < TDIM) orow[tid] = t * scale;
    v0.x *= scale; v0.y *= scale; v0.z *= scale; v0.w *= scale;
    v1.x *= scale; v1.y *= scale; v1.z *= scale; v1.w *= scale;
    *(float4*)&orow[TDIM + e0]     = v0;
    *(float4*)&orow[TDIM + e0 + 4] = v1;
}

// ---------------- launcher ----------------
extern "C" void kernel_launch(void* const* d_in, const int* in_sizes, int n_in,
                              void* d_out, int out_size, void* d_ws, size_t ws_size,
                              hipStream_t stream)
{
    const float* x       = (const float*)d_in[0];
    const float* Wf      = (const float*)d_in[1];
    const float* bf      = (const float*)d_in[2];
    const float* Ws      = (const float*)d_in[3];
    const float* bs      = (const float*)d_in[4];
    const float* Wt      = (const float*)d_in[5];
    const float* bt      = (const float*)d_in[6];
    const float* anchors = (const float*)d_in[7];
    const float* dust    = (const float*)d_in[8];
    const float* sharp   = (const float*)d_in[9];
    float* out = (float*)d_out;

    char* base = (char*)d_ws;
    short* W_pack        = (short*)base;                       // 294912 B
    float* bias_all      = (float*)(base + 294912);            // 192 fl -> end 295680 B
    float* Mmat          = bias_all + 192;                     // 2097152 fl (8.39 MB)
    unsigned short* fT   = (unsigned short*)(Mmat + (size_t)BATCH * KDIM * NM1); // 4194304 us (8.39 MB)
    float* u_buf         = (float*)(fT + (size_t)BATCH * CDIM * NM1);  // 2080 fl
    float* v_buf         = u_buf + BATCH * 65;                 // 32768 fl
    float* vpart         = v_buf + BATCH * NM1;                // 8*32*8192 fl (8.39 MB)
    float* rspart        = vpart + (size_t)NS_AGG * BATCH * KDIM * CDIM; // 16384 fl
    float* tpart         = rspart + NS_AGG * BATCH * KDIM;     // 24576 fl

    hipLaunchKernelGGL(prep, dim3(672), dim3(256), 0, stream,
                       Wf, Ws, bf, bs, x, Wt, W_pack, bias_all, tpart);
    hipLaunchKernelGGL(gemm_fs, dim3(512), dim3(256), 0, stream,
                       x, W_pack, bias_all, sharp, fT, Mmat);

    hipLaunchKernelGGL(HIP_KERNEL_NAME(sink_u<true>), dim3(520), dim3(256), 0, stream,
                       Mmat, v_buf, dust, u_buf);
    hipLaunchKernelGGL(sink_v, dim3(BATCH, 8), dim3(128), 0, stream,
                       Mmat, u_buf, dust, v_buf);
    for (int it = 1; it < NITER; ++it) {
        hipLaunchKernelGGL(HIP_KERNEL_NAME(sink_u<false>), dim3(520), dim3(256), 0, stream,
                           Mmat, v_buf, dust, u_buf);
        hipLaunchKernelGGL(sink_v, dim3(BATCH, 8), dim3(128), 0, stream,
                           Mmat, u_buf, dust, v_buf);
    }

    hipLaunchKernelGGL(aggregate, dim3(BATCH, NS_AGG), dim3(256), 0, stream,
                       Mmat, fT, u_buf, v_buf, vpart, rspart);
    hipLaunchKernelGGL(finalize_all, dim3(BATCH), dim3(1024), 0, stream,
                       vpart, rspart, anchors, tpart, bt, out);
}